// Round 6
// baseline (594.082 us; speedup 1.0000x reference)
//
#include <hip/hip_runtime.h>
#include <hip/hip_bf16.h>
#include <stdint.h>

typedef unsigned short u16;
typedef __attribute__((ext_vector_type(8))) short bf16x8;
typedef __attribute__((ext_vector_type(4))) float f32x4;

#define HEADS 8
#define DHEAD 128
#define NSEQ 1024
#define BATCH 4
#define DIM 1024
#define ATT_SCALE 0.088388347648318447f  // 1/sqrt(128)

static __device__ __forceinline__ float bf2f(u16 u){
  union { unsigned int i; float f; } c; c.i = ((unsigned int)u) << 16; return c.f;
}
static __device__ __forceinline__ u16 f2bf(float f){
  union { float f; unsigned int i; } c; c.f = f;
  unsigned int x = c.i;
  return (u16)((x + 0x7fffu + ((x >> 16) & 1u)) >> 16);
}

// async global->LDS, 16B per lane, dest = wave-uniform base + lane*16
static __device__ __forceinline__ void gload_lds16(const void* g, void* l){
  __builtin_amdgcn_global_load_lds((__attribute__((address_space(1))) void*)(g),
                                   (__attribute__((address_space(3))) void*)(l),
                                   16, 0, 0);
}

// ---------------- LayerNorm x3 fused: fp32 in, bf16 out ---------------------
// grid (4096, 3): y=0 x->xn (ln), y=1 ref->rn (ln), y=2 cinfo->cn (cln)
__global__ __launch_bounds__(256)
void ln3_kernel(const float* __restrict__ x, const float* __restrict__ ref,
                const float* __restrict__ cinfo,
                const float* __restrict__ ln_w, const float* __restrict__ ln_b,
                const float* __restrict__ cln_w, const float* __restrict__ cln_b,
                u16* __restrict__ xn, u16* __restrict__ rn, u16* __restrict__ cn)
{
  const int z = blockIdx.y;
  const float* src = (z==0) ? x : (z==1) ? ref : cinfo;
  const float* w   = (z==2) ? cln_w : ln_w;
  const float* b   = (z==2) ? cln_b : ln_b;
  u16* out         = (z==0) ? xn : (z==1) ? rn : cn;

  const int row = blockIdx.x;
  const int t = threadIdx.x;
  const float* xr = src + (size_t)row * DIM;
  float4 v4 = *(const float4*)(xr + t*4);
  float v[4] = {v4.x, v4.y, v4.z, v4.w};
  float s = v[0]+v[1]+v[2]+v[3];
  __shared__ float red[256];
  red[t] = s; __syncthreads();
  for (int o=128;o;o>>=1){ if (t<o) red[t]+=red[t+o]; __syncthreads(); }
  const float mean = red[0] * (1.0f/DIM);
  __syncthreads();
  s = 0.f;
#pragma unroll
  for (int i=0;i<4;i++){ float d = v[i]-mean; s += d*d; }
  red[t] = s; __syncthreads();
  for (int o=128;o;o>>=1){ if (t<o) red[t]+=red[t+o]; __syncthreads(); }
  const float rstd = rsqrtf(red[0]*(1.0f/DIM) + 1e-5f);
  float4 w4 = *(const float4*)(w + t*4);
  float4 b4 = *(const float4*)(b + t*4);
  float wv[4] = {w4.x, w4.y, w4.z, w4.w};
  float bv[4] = {b4.x, b4.y, b4.z, b4.w};
  union { uint2 u; u16 s[4]; } ov;
#pragma unroll
  for (int i=0;i<4;i++)
    ov.s[i] = f2bf((v[i]-mean)*rstd*wv[i] + bv[i]);
  *(uint2*)(out + (size_t)row*DIM + t*4) = ov.u;
}

// -------- weight convert+transpose: fp32 [K,1024] -> bf16 [1024,K] ----------
__global__ __launch_bounds__(256)
void wcvt_kernel(const float* __restrict__ Wk, const float* __restrict__ Wv,
                 const float* __restrict__ Wo,
                 u16* __restrict__ WkT, u16* __restrict__ WvT, u16* __restrict__ WoT)
{
  const int z = blockIdx.z;
  const int K = (z==0) ? 3072 : (z==1) ? 2048 : 1024;
  if ((int)blockIdx.x*32 >= K) return;
  const float* W = (z==0) ? Wk : (z==1) ? Wv : Wo;
  u16* WT = (z==0) ? WkT : (z==1) ? WvT : WoT;
  __shared__ float tile[32][33];
  const int k0 = blockIdx.x*32, n0 = blockIdx.y*32;
  const int t = threadIdx.x, tc = t&31, tr = t>>5;
#pragma unroll
  for (int p=0;p<4;p++)
    tile[tr+p*8][tc] = W[(size_t)(k0+tr+p*8)*DIM + n0+tc];
  __syncthreads();
#pragma unroll
  for (int p=0;p<4;p++)
    WT[(size_t)(n0+tr+p*8)*K + k0+tc] = f2bf(tile[tc][tr+p*8]);
}

// ---------- single-wave 64x64 GEMM: 64 threads/block, NO barriers ----------
// Each block = ONE wave owning a 64x64 C-tile with private 16 KB LDS (2-buf).
// Rationale: grid-starved GEMMs (steps 2,7) had 2 coupled blocks/CU; this
// gives 8 INDEPENDENT single-wave pipelines/CU. Wave-synchronous: no
// __syncthreads ever; counted "s_waitcnt vmcnt(8)" keeps the next tile's
// 8 staging loads in flight while computing the current one.
// LDS layout per 32-k tile: 4 blocks of 16 rows; slot l (16B) of block f =
// [row f*16+(l&15)][k-oct l>>4] -> ds_read_b128 at base+lane*16, 0 conflicts.
// Fragment/MFMA math identical to the verified gemm_kernel wave path (wm=wn=0).
// Block id: XCD-chunk swizzle (grid%8==0), then (zz, x, y) decomposition so
// each XCD works one (side, x-panel) group -> B-tiles + sliding A-window fit L2.
// epi: 0 bf16 plane | 1 bf16 head-merge | 2 fp32 +bias | 3 bf16 head-split
//      | 4 fp32 head-merge   (same codes as gemm_kernel)
__global__ __launch_bounds__(64)
void gemm1w_kernel(const u16* __restrict__ A0, const u16* __restrict__ A1,
                   const u16* __restrict__ A2, const u16* __restrict__ A0b,
                   const u16* __restrict__ A1b,
                   const u16* __restrict__ B1, const u16* __restrict__ B2,
                   void* __restrict__ Cv, void* __restrict__ Cv2,
                   const float* __restrict__ bias,
                   int K1, int K2, int lda, int ldb1, int ldb2, int ldc,
                   long a_plane, long b_plane, long c_plane,
                   int epi1, int epi2, int z_split, int NXT, int NYT,
                   float alpha)
{
  __shared__ __attribute__((aligned(16))) u16 sA[2][2048];
  __shared__ __attribute__((aligned(16))) u16 sB[2][2048];
  const int lane = threadIdx.x;
  const int nb = gridDim.x;
  const int bid = blockIdx.x;
  const int swz = (bid & 7)*(nb >> 3) + (bid >> 3);   // XCD chunking (nb%8==0)
  const int per_z = NXT*NYT;
  const int zz = swz / per_z;
  const int rr_ = swz - zz*per_z;
  const int x  = rr_ / NYT;
  const int y  = rr_ - x*NYT;
  const int m0 = y*64, n0 = x*64;
  const bool side = (zz >= z_split);
  const int z = side ? (zz - z_split) : zz;
  const u16* a0 = (side ? A0b : A0) + (size_t)z*a_plane;
  const u16* a1 = (side ? A1b : A1) + (size_t)z*a_plane;
  const u16* a2 = A2 + (size_t)z*a_plane;
  const u16* bB = (side ? B2 : B1) + (size_t)z*b_plane;
  void* Cp = side ? Cv2 : Cv;
  const int EPI = side ? epi2 : epi1;
  const int K   = side ? K2 : K1;
  const int ldb = side ? ldb2 : ldb1;

  const int lm = lane&15, q = lane>>4;

  const f32x4 zero4 = {0.f,0.f,0.f,0.f};
  f32x4 acc[4][4];
#pragma unroll
  for (int i=0;i<4;i++)
#pragma unroll
    for (int j=0;j<4;j++) acc[i][j] = zero4;

  auto issueA = [&](int kt, int buf){
    const int kg = kt<<5, seg = kg>>10, ka = kg&1023;
    const u16* Ap = (seg==0) ? a0 : (seg==1 ? a1 : a2);
#pragma unroll
    for (int rr=0; rr<4; ++rr)
      gload_lds16(Ap + (size_t)(m0+rr*16+lm)*lda + (ka + q*8), &sA[buf][rr*512]);
  };
  auto issueB = [&](int kt, int buf){
    const int kg = kt<<5;
#pragma unroll
    for (int rr=0; rr<4; ++rr)
      gload_lds16(bB + (size_t)(n0+rr*16+lm)*ldb + (kg + q*8), &sB[buf][rr*512]);
  };

  const int KT = K >> 5;
  issueA(0, 0);
  issueB(0, 0);

  int cur = 0;
  for (int kt=0; kt<KT; ++kt){
    if (kt+1 < KT){
      issueA(kt+1, cur^1);                      // next tile: 8 loads in flight
      issueB(kt+1, cur^1);
      asm volatile("s_waitcnt vmcnt(8)" ::: "memory");   // wait tile kt only
    } else {
      asm volatile("s_waitcnt vmcnt(0)" ::: "memory");
    }
    bf16x8 af[4], bfr[4];
#pragma unroll
    for (int f=0; f<4; ++f){
      af[f]  = *(const bf16x8*)&sA[cur][f*512 + lane*8];
      bfr[f] = *(const bf16x8*)&sB[cur][f*512 + lane*8];
    }
#pragma unroll
    for (int fm=0; fm<4; ++fm)
#pragma unroll
      for (int fn=0; fn<4; ++fn)
        acc[fm][fn] = __builtin_amdgcn_mfma_f32_16x16x32_bf16(af[fm], bfr[fn], acc[fm][fn], 0, 0, 0);
    cur ^= 1;
  }

#pragma unroll
  for (int fm=0; fm<4; ++fm){
#pragma unroll
    for (int fn=0; fn<4; ++fn){
#pragma unroll
      for (int r=0; r<4; ++r){
        const int m = m0 + fm*16 + q*4 + r;
        const int n = n0 + fn*16 + lm;
        float val = acc[fm][fn][r] * alpha;
        if (EPI == 0){
          ((u16*)Cp)[(size_t)z*c_plane + (size_t)m*ldc + n] = f2bf(val);
        } else if (EPI == 1){
          ((u16*)Cp)[((size_t)(z>>3)*NSEQ + m)*DIM + (size_t)(z&7)*DHEAD + n] = f2bf(val);
        } else if (EPI == 2){
          ((float*)Cp)[(size_t)m*ldc + n] = val + bias[n];
        } else if (EPI == 3){
          ((u16*)Cp)[(size_t)(((m>>10)*HEADS + (n>>7))*NSEQ + (m&1023))*DHEAD + (n&127)] = f2bf(val);
        } else {
          ((float*)Cp)[((size_t)(z>>3)*NSEQ + m)*DIM + (size_t)(z&7)*DHEAD + n] = val;
        }
      }
    }
  }
}

// ---------------- MFMA GEMM: dbuf + global_load_lds, conflict-free LDS ------
// (used for step 4 only, BK=32: 2048 blocks already give good occupancy)
template<int BK>
__global__ __launch_bounds__(256)
void gemm_kernel(const u16* __restrict__ A0, const u16* __restrict__ A1,
                 const u16* __restrict__ A2, const u16* __restrict__ A0b,
                 const u16* __restrict__ A1b,
                 const u16* __restrict__ B1, const u16* __restrict__ B2,
                 void* __restrict__ Cv, void* __restrict__ Cv2,
                 const float* __restrict__ bias,
                 int K1, int K2, int lda, int ldb1, int ldb2, int ldc,
                 long a_plane, long b_plane, long c_plane,
                 int epi1, int epi2, int z_split, float alpha)
{
  constexpr int SUBS = BK/32;
  __shared__ __attribute__((aligned(16))) u16 sA[2][SUBS*4096];
  __shared__ __attribute__((aligned(16))) u16 sB[2][SUBS*4096];
  const int t = threadIdx.x;
  const int m0 = blockIdx.y*128, n0 = blockIdx.x*128;
  const int zz = blockIdx.z;
  const bool side = (zz >= z_split);
  const int z = side ? (zz - z_split) : zz;
  const u16* a0 = (side ? A0b : A0) + (size_t)z*a_plane;
  const u16* a1 = (side ? A1b : A1) + (size_t)z*a_plane;
  const u16* a2 = A2 + (size_t)z*a_plane;
  const u16* bB = (side ? B2 : B1) + (size_t)z*b_plane;
  void* Cp = side ? Cv2 : Cv;
  const int EPI = side ? epi2 : epi1;
  const int K   = side ? K2 : K1;
  const int ldb = side ? ldb2 : ldb1;

  const int wave = t>>6, lane = t&63;
  const int wm = (wave>>1)*64, wn = (wave&1)*64;
  const int lm = lane&15, q = lane>>4;

  const f32x4 zero4 = {0.f,0.f,0.f,0.f};
  f32x4 acc[4][4];
#pragma unroll
  for (int i=0;i<4;i++)
#pragma unroll
    for (int j=0;j<4;j++) acc[i][j] = zero4;

  const int arowblk = wave*32;

  const int KT = K / BK;

  auto issueA = [&](int kt, int buf){
    const int kg = kt*BK, seg = kg>>10, ka = kg&1023;
    const u16* Ap = (seg==0) ? a0 : (seg==1 ? a1 : a2);
#pragma unroll
    for (int sub=0; sub<SUBS; ++sub)
#pragma unroll
      for (int rr=0; rr<2; ++rr){
        const int rb = arowblk + rr*16;
        gload_lds16(Ap + (size_t)(m0+rb+lm)*lda + (ka + sub*32 + q*8),
                    &sA[buf][sub*4096 + rb*32]);
      }
  };
  auto issueB = [&](int kt, int buf){
    const int kg = kt*BK;
#pragma unroll
    for (int sub=0; sub<SUBS; ++sub)
#pragma unroll
      for (int rr=0; rr<2; ++rr){
        const int rb = arowblk + rr*16;
        gload_lds16(bB + (size_t)(n0+rb+lm)*ldb + (kg + sub*32 + q*8),
                    &sB[buf][sub*4096 + rb*32]);
      }
  };

  issueA(0, 0);
  issueB(0, 0);

  int cur = 0;
  for (int kt=0; kt<KT; ++kt){
    __syncthreads();
    if (kt+1 < KT){
      issueA(kt+1, cur^1);
      issueB(kt+1, cur^1);
    }
#pragma unroll
    for (int sub=0; sub<SUBS; ++sub){
      bf16x8 af[4], bfr[4];
#pragma unroll
      for (int f=0; f<4; ++f){
        af[f]  = *(const bf16x8*)&sA[cur][sub*4096 + ((wm>>4)+f)*512 + lane*8];
        bfr[f] = *(const bf16x8*)&sB[cur][sub*4096 + ((wn>>4)+f)*512 + lane*8];
      }
#pragma unroll
      for (int fm=0; fm<4; ++fm)
#pragma unroll
        for (int fn=0; fn<4; ++fn)
          acc[fm][fn] = __builtin_amdgcn_mfma_f32_16x16x32_bf16(af[fm], bfr[fn], acc[fm][fn], 0, 0, 0);
    }
    cur ^= 1;
  }

#pragma unroll
  for (int fm=0; fm<4; ++fm){
#pragma unroll
    for (int fn=0; fn<4; ++fn){
#pragma unroll
      for (int r=0; r<4; ++r){
        const int m = m0 + wm + fm*16 + q*4 + r;
        const int n = n0 + wn + fn*16 + lm;
        float val = acc[fm][fn][r] * alpha;
        if (EPI == 0){
          ((u16*)Cp)[(size_t)z*c_plane + (size_t)m*ldc + n] = f2bf(val);
        } else if (EPI == 1){
          ((u16*)Cp)[((size_t)(z>>3)*NSEQ + m)*DIM + (size_t)(z&7)*DHEAD + n] = f2bf(val);
        } else if (EPI == 2){
          ((float*)Cp)[(size_t)m*ldc + n] = val + bias[n];
        } else if (EPI == 3){
          ((u16*)Cp)[(size_t)(((m>>10)*HEADS + (n>>7))*NSEQ + (m&1023))*DHEAD + (n&127)] = f2bf(val);
        } else {
          ((float*)Cp)[((size_t)(z>>3)*NSEQ + m)*DIM + (size_t)(z&7)*DHEAD + n] = val;
        }
      }
    }
  }
}

// ------- split-K final projection: out_pre[4096,1024] @ WoT -> partials -----
__global__ __launch_bounds__(256)
void gemm8_kernel(const u16* __restrict__ A, const u16* __restrict__ B,
                  float* __restrict__ P)
{
  __shared__ __attribute__((aligned(16))) u16 sA[2][4096];
  __shared__ __attribute__((aligned(16))) u16 sB[2][4096];
  const int t = threadIdx.x;
  const int bid = blockIdx.x;
  const int w = (bid & 7)*128 + (bid >> 3);
  const int x = w & 7;          // N tile (0..7)
  const int y = (w >> 3) & 31;  // M tile (0..31)
  const int s = w >> 8;         // K slice (0..3)
  const int m0 = y*128, n0 = x*128, k0 = s*256;

  const int wave = t>>6, lane = t&63;
  const int wm = (wave>>1)*64, wn = (wave&1)*64;
  const int lm = lane&15, q = lane>>4;

  const f32x4 zero4 = {0.f,0.f,0.f,0.f};
  f32x4 acc[4][4];
#pragma unroll
  for (int i=0;i<4;i++)
#pragma unroll
    for (int j=0;j<4;j++) acc[i][j] = zero4;

  const int arowblk = wave*32;

  auto issueA = [&](int kt, int buf){
    const int kg = k0 + (kt<<5);
#pragma unroll
    for (int rr=0; rr<2; ++rr){
      const int rb = arowblk + rr*16;
      gload_lds16(A + (size_t)(m0+rb+lm)*1024 + (kg + q*8), &sA[buf][rb*32]);
    }
  };
  auto issueB = [&](int kt, int buf){
    const int kg = k0 + (kt<<5);
#pragma unroll
    for (int rr=0; rr<2; ++rr){
      const int rb = arowblk + rr*16;
      gload_lds16(B + (size_t)(n0+rb+lm)*1024 + (kg + q*8), &sB[buf][rb*32]);
    }
  };

  issueA(0, 0); issueB(0, 0);

  int cur = 0;
  for (int kt=0; kt<8; ++kt){
    __syncthreads();
    if (kt+1 < 8){
      issueA(kt+1, cur^1);
      issueB(kt+1, cur^1);
    }
    bf16x8 af[4], bfr[4];
#pragma unroll
    for (int f=0; f<4; ++f){
      af[f]  = *(const bf16x8*)&sA[cur][((wm>>4)+f)*512 + lane*8];
      bfr[f] = *(const bf16x8*)&sB[cur][((wn>>4)+f)*512 + lane*8];
    }
#pragma unroll
    for (int fm=0; fm<4; ++fm)
#pragma unroll
      for (int fn=0; fn<4; ++fn)
        acc[fm][fn] = __builtin_amdgcn_mfma_f32_16x16x32_bf16(af[fm], bfr[fn], acc[fm][fn], 0, 0, 0);
    cur ^= 1;
  }

  float* Pp = P + (size_t)s*4194304;   // 4096*1024 per slice
#pragma unroll
  for (int fm=0; fm<4; ++fm){
#pragma unroll
    for (int fn=0; fn<4; ++fn){
#pragma unroll
      for (int r=0; r<4; ++r){
        const int m = m0 + wm + fm*16 + q*4 + r;
        const int n = n0 + wn + fn*16 + lm;
        Pp[(size_t)m*1024 + n] = acc[fm][fn][r];
      }
    }
  }
}

// ------- reduce 4 fp32 partial planes + bias -> out (fp32) ------------------
__global__ __launch_bounds__(256)
void red8_kernel(const float* __restrict__ P, const float* __restrict__ bias,
                 float* __restrict__ out)
{
  const int idx = blockIdx.x*256 + threadIdx.x;   // float4 index, 1M total
  const float4* P4 = (const float4*)P;
  float4 a = P4[idx];
  float4 b = P4[idx + 1048576];
  float4 c = P4[idx + 2097152];
  float4 d = P4[idx + 3145728];
  float4 bb = ((const float4*)bias)[idx & 255];
  float4 o;
  o.x = a.x + b.x + c.x + d.x + bb.x;
  o.y = a.y + b.y + c.y + d.y + bb.y;
  o.z = a.z + b.z + c.z + d.z + bb.z;
  o.w = a.w + b.w + c.w + d.w + bb.w;
  ((float4*)out)[idx] = o;
}

// ------- transpose both operands: [32][1024][128] -> [32][128][1024] --------
__global__ __launch_bounds__(256)
void transpose2_kernel(const u16* __restrict__ cond, const u16* __restrict__ refv,
                       u16* __restrict__ condT, u16* __restrict__ refvT)
{
  __shared__ u16 tile[32][33];
  const int zz = blockIdx.z;
  const u16* X = (zz < 32) ? cond : refv;
  u16* XT      = (zz < 32) ? condT : refvT;
  const int z = zz & 31;
  const int i0 = blockIdx.y*32, d0 = blockIdx.x*32;
  const int t = threadIdx.x;
  const int tc = t & 31, tr = t >> 5;
  const u16* Xp = X + (size_t)z*NSEQ*DHEAD;
#pragma unroll
  for (int p=0;p<4;p++){
    int i = tr + p*8;
    tile[i][tc] = Xp[(size_t)(i0+i)*DHEAD + d0 + tc];
  }
  __syncthreads();
  u16* Op = XT + (size_t)z*DHEAD*NSEQ;
#pragma unroll
  for (int p=0;p<4;p++){
    int d = tr + p*8;
    Op[(size_t)(d0+d)*NSEQ + i0 + tc] = tile[tc][d];
  }
}

// ---------------- softmax stats: row + col fused in one launch ---------------
__global__ __launch_bounds__(256)
void stats_kernel(const u16* __restrict__ sim,
                  float* __restrict__ rmax, float* __restrict__ rrcp,
                  float* __restrict__ cmax, float* __restrict__ crcp)
{
  __shared__ float smx[4][64], ssm[4][64];
  if (blockIdx.x < 8192){
    const int wave = threadIdx.x >> 6, lane = threadIdx.x & 63;
    const int row = blockIdx.x*4 + wave;   // (b*8+h)*1024+i
    const u16* sr = sim + (size_t)row * NSEQ;
    float v[16]; float m = -1e30f;
#pragma unroll
    for (int c=0;c<16;c++){ v[c] = bf2f(sr[lane + c*64]); m = fmaxf(m, v[c]); }
#pragma unroll
    for (int off=32; off; off>>=1) m = fmaxf(m, __shfl_xor(m, off));
    float s = 0.f;
#pragma unroll
    for (int c=0;c<16;c++) s += __expf(v[c]-m);
#pragma unroll
    for (int off=32; off; off>>=1) s += __shfl_xor(s, off);
    if (lane == 0){ rmax[row] = m; rrcp[row] = 1.0f/s; }
  } else {
    const int t = threadIdx.x;
    const int jl = t & 63, slice = t >> 6;
    const int c = (blockIdx.x - 8192)*64 + jl;   // (b*8+h)*1024 + j
    const int bh = c >> 10, j = c & 1023;
    const u16* sp = sim + (size_t)bh*NSEQ*NSEQ + j + (size_t)(slice*256)*NSEQ;
    float m0=-1e30f, m1=-1e30f, m2=-1e30f, m3=-1e30f;
    for (int i=0;i<256;i+=4){
      m0 = fmaxf(m0, bf2f(sp[(size_t)(i  )*NSEQ]));
      m1 = fmaxf(m1, bf2f(sp[(size_t)(i+1)*NSEQ]));
      m2 = fmaxf(m2, bf2f(sp[(size_t)(i+2)*NSEQ]));
      m3 = fmaxf(m3, bf2f(sp[(size_t)(i+3)*NSEQ]));
    }
    smx[slice][jl] = fmaxf(fmaxf(m0,m1), fmaxf(m2,m3));
    __syncthreads();
    const float M = fmaxf(fmaxf(smx[0][jl], smx[1][jl]),
                          fmaxf(smx[2][jl], smx[3][jl]));
    float s0=0.f, s1=0.f, s2=0.f, s3=0.f;
    for (int i=0;i<256;i+=4){
      s0 += __expf(bf2f(sp[(size_t)(i  )*NSEQ]) - M);
      s1 += __expf(bf2f(sp[(size_t)(i+1)*NSEQ]) - M);
      s2 += __expf(bf2f(sp[(size_t)(i+2)*NSEQ]) - M);
      s3 += __expf(bf2f(sp[(size_t)(i+3)*NSEQ]) - M);
    }
    ssm[slice][jl] = s0+s1+s2+s3;
    __syncthreads();
    if (slice == 0){
      float S = ssm[0][jl] + ssm[1][jl] + ssm[2][jl] + ssm[3][jl];
      cmax[c] = M; crcp[c] = 1.0f/S;
    }
  }
}

// ---------------- softmax + talking-heads mix ----------------
__global__ __launch_bounds__(256)
void mix_kernel(u16* simam,
                const float* __restrict__ rmax, const float* __restrict__ rrcp,
                const float* __restrict__ cmax, const float* __restrict__ crcp,
                const float* __restrict__ thw, const float* __restrict__ cthw,
                u16* __restrict__ cmT)
{
  __shared__ float s_th[64], s_cth[64];
  __shared__ u16 s_cm[8][32][33];
  const int t = threadIdx.x;
  if (t < 64){ s_th[t] = thw[t]; s_cth[t] = cthw[t]; }
  __syncthreads();
  const int b = blockIdx.z, i0 = blockIdx.y*32, j0 = blockIdx.x*32;
  const int tj = t & 31, ti = t >> 5;
  for (int p=0;p<4;p++){
    const int i = ti + p*8;
    float a[8], c[8];
#pragma unroll
    for (int h=0;h<8;h++){
      const int bh = b*8 + h;
      const float v = bf2f(simam[((size_t)bh*NSEQ + (i0+i))*NSEQ + j0 + tj]);
      a[h] = __expf(v - rmax[(size_t)bh*NSEQ + i0+i]) * rrcp[(size_t)bh*NSEQ + i0+i];
      c[h] = __expf(v - cmax[(size_t)bh*NSEQ + j0+tj]) * crcp[(size_t)bh*NSEQ + j0+tj];
    }
#pragma unroll
    for (int g=0;g<8;g++){
      float sa = 0.f, sc = 0.f;
#pragma unroll
      for (int h=0;h<8;h++){ sa += s_th[g*8+h]*a[h]; sc += s_cth[g*8+h]*c[h]; }
      simam[((size_t)(b*8+g)*NSEQ + (i0+i))*NSEQ + j0 + tj] = f2bf(sa);
      s_cm[g][i][tj] = f2bf(sc);
    }
  }
  __syncthreads();
#pragma unroll
  for (int g=0;g<8;g++){
#pragma unroll
    for (int p=0;p<4;p++){
      const int j = ti + p*8;
      cmT[((size_t)(b*8+g)*NSEQ + (j0+j))*NSEQ + i0 + tj] = s_cm[g][tj][j];
    }
  }
}

extern "C" void kernel_launch(void* const* d_in, const int* in_sizes, int n_in,
                              void* d_out, int out_size, void* d_ws, size_t ws_size,
                              hipStream_t stream)
{
  const float* x     = (const float*)d_in[0];
  const float* cinfo = (const float*)d_in[1];
  const float* ref   = (const float*)d_in[2];
  const float* ln_w  = (const float*)d_in[3];
  const float* ln_b  = (const float*)d_in[4];
  const float* cln_w = (const float*)d_in[5];
  const float* cln_b = (const float*)d_in[6];
  const float* Wk    = (const float*)d_in[7];
  const float* Wv    = (const float*)d_in[8];
  const float* Wo    = (const float*)d_in[9];
  const float* bo    = (const float*)d_in[10];
  const float* thw   = (const float*)d_in[11];
  const float* cthw  = (const float*)d_in[12];
  float* out = (float*)d_out;

  char* ws = (char*)d_ws;
  u16* xn    = (u16*)(ws + 0);          // 8 MB; reused as out_pre
  u16* cn    = (u16*)(ws + 8388608);    // 8 MB; reused for softmax stats
  u16* rn    = (u16*)(ws + 16777216);   // 8 MB
  u16* cond  = (u16*)(ws + 25165824);   // 8 MB  [b,h,i,d]
  u16* refv  = (u16*)(ws + 33554432);   // 8 MB  [b,h,j,d]
  u16* condT = (u16*)(ws + 41943040);   // 8 MB  [b,h,d,j]
  u16* refvT = (u16*)(ws + 50331648);   // 8 MB  [b,h,d,j]
  u16* sim   = (u16*)(ws + 58720256);   // 64 MB [b,h,i,j]; becomes am in-place;
                                        //        reused as fp32 partials for step 8
  u16* cmT   = (u16*)(ws + 125829120);  // 64 MB [b,g,j,i]
  u16* WkT   = (u16*)(ws + 192937984);  // 6 MB  [1024,3072] bf16
  u16* WvT   = (u16*)(ws + 199229440);  // 4 MB  [1024,2048] bf16
  u16* WoT   = (u16*)(ws + 203423744);  // 2 MB  [1024,1024] bf16
  float* rmax = (float*)(ws + 8388608);
  float* rrcp = (float*)(ws + 8388608 + 131072);
  float* cmax = (float*)(ws + 8388608 + 262144);
  float* crcp = (float*)(ws + 8388608 + 393216);
  u16* out_pre = (u16*)(ws + 0);

  // 1) LayerNorms (fp32 -> bf16), all three in one launch
  ln3_kernel<<<dim3(4096,3), 256, 0, stream>>>(x, ref, cinfo, ln_w, ln_b,
                                               cln_w, cln_b, xn, rn, cn);

  // 1b) weight convert+transpose fp32[K,N] -> bf16[N,K]
  wcvt_kernel<<<dim3(96,32,3), 256, 0, stream>>>(Wk, Wv, Wo, WkT, WvT, WoT);

  // 2) fused projections, single-wave 64x64 blocks (8 independent waves/CU):
  //    zz=0 -> [xn|cn|rn]@Wk -> cond; zz=1 -> [xn|rn]@Wv -> refv
  gemm1w_kernel<<<2048, 64, 0, stream>>>(
      xn, cn, rn, xn, rn, WkT, WvT, cond, refv, nullptr,
      3072, 2048, DIM, 3072, 2048, 0, 0, 0, 0, 3, 3, 1, 16, 64, 1.0f);

  // 3) transposed copies for the PV/context GEMM B-operands (one launch)
  transpose2_kernel<<<dim3(4,32,64), 256, 0, stream>>>(cond, refv, condT, refvT);

  // 4) sim = cond @ refv^T * scale  (per (b,h) plane; 2048 blocks, BK=32)
  gemm_kernel<32><<<dim3(8,8,32), 256, 0, stream>>>(
      cond, cond, cond, cond, cond, refv, refv, sim, sim, nullptr,
      DHEAD, DHEAD, DHEAD, DHEAD, DHEAD, NSEQ,
      (long)NSEQ*DHEAD, (long)NSEQ*DHEAD, (long)NSEQ*NSEQ, 0, 0, 1000000, ATT_SCALE);

  // 5) softmax stats (row + col in one launch; col is 2-pass max/sum)
  stats_kernel<<<8704, 256, 0, stream>>>(sim, rmax, rrcp, cmax, crcp);

  // 6) both softmaxes + talking heads (am in-place over sim; cmT transposed)
  mix_kernel<<<dim3(32,32,4), 256, 0, stream>>>(sim, rmax, rrcp, cmax, crcp, thw, cthw, cmT);

  // 7) fused PV + context, single-wave 64x64 blocks:
  //    zz<32: am@refvT -> out_pre (bf16 head-merge); zz>=32: cmT@condT -> ctx (fp32)
  gemm1w_kernel<<<2048, 64, 0, stream>>>(
      sim, sim, sim, cmT, cmT, refvT, condT, out_pre, out + (size_t)BATCH*NSEQ*DIM, nullptr,
      1024, 1024, NSEQ, NSEQ, NSEQ, 0,
      (long)NSEQ*NSEQ, (long)DHEAD*NSEQ, 0, 1, 4, 32, 2, 16, 1.0f);

  // 8) final projection, split-K=4 + chunked XCD swizzle: partials into sim
  //    region (dead after step 7), then deterministic reduce + bias.
  gemm8_kernel<<<1024, 256, 0, stream>>>(out_pre, WoT, (float*)sim);
  red8_kernel<<<4096, 256, 0, stream>>>((const float*)sim, bo, out);
}

// Round 7
// 524.939 us; speedup vs baseline: 1.1317x; 1.1317x over previous
//
#include <hip/hip_runtime.h>
#include <hip/hip_bf16.h>
#include <stdint.h>

typedef unsigned short u16;
typedef __attribute__((ext_vector_type(8))) short bf16x8;
typedef __attribute__((ext_vector_type(4))) float f32x4;

#define HEADS 8
#define DHEAD 128
#define NSEQ 1024
#define BATCH 4
#define DIM 1024
#define ATT_SCALE 0.088388347648318447f  // 1/sqrt(128)

static __device__ __forceinline__ float bf2f(u16 u){
  union { unsigned int i; float f; } c; c.i = ((unsigned int)u) << 16; return c.f;
}
static __device__ __forceinline__ u16 f2bf(float f){
  union { float f; unsigned int i; } c; c.f = f;
  unsigned int x = c.i;
  return (u16)((x + 0x7fffu + ((x >> 16) & 1u)) >> 16);
}

// async global->LDS, 16B per lane, dest = wave-uniform base + lane*16
static __device__ __forceinline__ void gload_lds16(const void* g, void* l){
  __builtin_amdgcn_global_load_lds((__attribute__((address_space(1))) void*)(g),
                                   (__attribute__((address_space(3))) void*)(l),
                                   16, 0, 0);
}

// ---------------- LayerNorm x3 fused: fp32 in, bf16 out ---------------------
// grid (4096, 3): y=0 x->xn (ln), y=1 ref->rn (ln), y=2 cinfo->cn (cln)
__global__ __launch_bounds__(256)
void ln3_kernel(const float* __restrict__ x, const float* __restrict__ ref,
                const float* __restrict__ cinfo,
                const float* __restrict__ ln_w, const float* __restrict__ ln_b,
                const float* __restrict__ cln_w, const float* __restrict__ cln_b,
                u16* __restrict__ xn, u16* __restrict__ rn, u16* __restrict__ cn)
{
  const int z = blockIdx.y;
  const float* src = (z==0) ? x : (z==1) ? ref : cinfo;
  const float* w   = (z==2) ? cln_w : ln_w;
  const float* b   = (z==2) ? cln_b : ln_b;
  u16* out         = (z==0) ? xn : (z==1) ? rn : cn;

  const int row = blockIdx.x;
  const int t = threadIdx.x;
  const float* xr = src + (size_t)row * DIM;
  float4 v4 = *(const float4*)(xr + t*4);
  float v[4] = {v4.x, v4.y, v4.z, v4.w};
  float s = v[0]+v[1]+v[2]+v[3];
  __shared__ float red[256];
  red[t] = s; __syncthreads();
  for (int o=128;o;o>>=1){ if (t<o) red[t]+=red[t+o]; __syncthreads(); }
  const float mean = red[0] * (1.0f/DIM);
  __syncthreads();
  s = 0.f;
#pragma unroll
  for (int i=0;i<4;i++){ float d = v[i]-mean; s += d*d; }
  red[t] = s; __syncthreads();
  for (int o=128;o;o>>=1){ if (t<o) red[t]+=red[t+o]; __syncthreads(); }
  const float rstd = rsqrtf(red[0]*(1.0f/DIM) + 1e-5f);
  float4 w4 = *(const float4*)(w + t*4);
  float4 b4 = *(const float4*)(b + t*4);
  float wv[4] = {w4.x, w4.y, w4.z, w4.w};
  float bv[4] = {b4.x, b4.y, b4.z, b4.w};
  union { uint2 u; u16 s[4]; } ov;
#pragma unroll
  for (int i=0;i<4;i++)
    ov.s[i] = f2bf((v[i]-mean)*rstd*wv[i] + bv[i]);
  *(uint2*)(out + (size_t)row*DIM + t*4) = ov.u;
}

// -------- weight convert+transpose: fp32 [K,1024] -> bf16 [1024,K] ----------
__global__ __launch_bounds__(256)
void wcvt_kernel(const float* __restrict__ Wk, const float* __restrict__ Wv,
                 const float* __restrict__ Wo,
                 u16* __restrict__ WkT, u16* __restrict__ WvT, u16* __restrict__ WoT)
{
  const int z = blockIdx.z;
  const int K = (z==0) ? 3072 : (z==1) ? 2048 : 1024;
  if ((int)blockIdx.x*32 >= K) return;
  const float* W = (z==0) ? Wk : (z==1) ? Wv : Wo;
  u16* WT = (z==0) ? WkT : (z==1) ? WvT : WoT;
  __shared__ float tile[32][33];
  const int k0 = blockIdx.x*32, n0 = blockIdx.y*32;
  const int t = threadIdx.x, tc = t&31, tr = t>>5;
#pragma unroll
  for (int p=0;p<4;p++)
    tile[tr+p*8][tc] = W[(size_t)(k0+tr+p*8)*DIM + n0+tc];
  __syncthreads();
#pragma unroll
  for (int p=0;p<4;p++)
    WT[(size_t)(n0+tr+p*8)*K + k0+tc] = f2bf(tile[tc][tr+p*8]);
}

// ------- split-K projections: 1280 blocks = 5 blk/CU (32KB LDS cap) ---------
// cond (K=3072, 3 slices aligned to A segs xn/cn/rn) and refv (K=2048,
// 2 slices xn/rn) in one launch. 128x128 tile, BK=32, identical inner loop to
// the verified gemm_kernel. XCD-chunk swizzle (1280%8==0, chunk 160).
// fp32 partials: Pc [3][4096][1024], Pr [2][4096][1024].
__global__ __launch_bounds__(256)
void gemmsk2_kernel(const u16* __restrict__ xn, const u16* __restrict__ cn,
                    const u16* __restrict__ rn,
                    const u16* __restrict__ WkT, const u16* __restrict__ WvT,
                    float* __restrict__ Pc, float* __restrict__ Pr)
{
  __shared__ __attribute__((aligned(16))) u16 sA[2][4096];
  __shared__ __attribute__((aligned(16))) u16 sB[2][4096];
  const int t = threadIdx.x;
  const int bid = blockIdx.x;
  const int swz = (bid & 7)*160 + (bid >> 3);     // XCD chunking
  const bool condside = swz < 768;
  const int w = condside ? swz : swz - 768;
  const int s = w >> 8;                           // slice (cond 0..2, refv 0..1)
  const int rem = w & 255;
  const int x = rem & 7, y = rem >> 3;
  const int m0 = y*128, n0 = x*128;
  const u16* A = condside ? (s==0 ? xn : (s==1 ? cn : rn))
                          : (s==0 ? xn : rn);
  const u16* B = (condside ? WkT : WvT) + s*1024; // column offset into weight
  const int ldb = condside ? 3072 : 2048;
  float* P = (condside ? Pc : Pr) + (size_t)s*4194304;

  const int wave = t>>6, lane = t&63;
  const int wm = (wave>>1)*64, wn = (wave&1)*64;
  const int lm = lane&15, q = lane>>4;

  const f32x4 zero4 = {0.f,0.f,0.f,0.f};
  f32x4 acc[4][4];
#pragma unroll
  for (int i=0;i<4;i++)
#pragma unroll
    for (int j=0;j<4;j++) acc[i][j] = zero4;

  const int arowblk = wave*32;

  auto issueA = [&](int kt, int buf){
    const int kg = kt<<5;
#pragma unroll
    for (int rr=0; rr<2; ++rr){
      const int rb = arowblk + rr*16;
      gload_lds16(A + (size_t)(m0+rb+lm)*1024 + (kg + q*8), &sA[buf][rb*32]);
    }
  };
  auto issueB = [&](int kt, int buf){
    const int kg = kt<<5;
#pragma unroll
    for (int rr=0; rr<2; ++rr){
      const int rb = arowblk + rr*16;
      gload_lds16(B + (size_t)(n0+rb+lm)*ldb + (kg + q*8), &sB[buf][rb*32]);
    }
  };

  issueA(0, 0); issueB(0, 0);

  int cur = 0;
  for (int kt=0; kt<32; ++kt){                    // 1024 / 32
    __syncthreads();
    if (kt+1 < 32){
      issueA(kt+1, cur^1);
      issueB(kt+1, cur^1);
    }
    bf16x8 af[4], bfr[4];
#pragma unroll
    for (int f=0; f<4; ++f){
      af[f]  = *(const bf16x8*)&sA[cur][((wm>>4)+f)*512 + lane*8];
      bfr[f] = *(const bf16x8*)&sB[cur][((wn>>4)+f)*512 + lane*8];
    }
#pragma unroll
    for (int fm=0; fm<4; ++fm)
#pragma unroll
      for (int fn=0; fn<4; ++fn)
        acc[fm][fn] = __builtin_amdgcn_mfma_f32_16x16x32_bf16(af[fm], bfr[fn], acc[fm][fn], 0, 0, 0);
    cur ^= 1;
  }

#pragma unroll
  for (int fm=0; fm<4; ++fm){
#pragma unroll
    for (int fn=0; fn<4; ++fn){
#pragma unroll
      for (int r=0; r<4; ++r){
        const int m = m0 + wm + fm*16 + q*4 + r;
        const int n = n0 + wn + fn*16 + lm;
        P[(size_t)m*1024 + n] = acc[fm][fn][r];
      }
    }
  }
}

// ------- reduce split-K partials -> head-split bf16 cond / refv -------------
// grid 8192: bid<4096 cond (3 planes), else refv (2 planes). One float4/thread.
__global__ __launch_bounds__(256)
void redsk2_kernel(const float* __restrict__ Pc, const float* __restrict__ Pr,
                   u16* __restrict__ cond, u16* __restrict__ refv)
{
  const int bid = blockIdx.x;
  const bool condside = bid < 4096;
  const int idx = (condside ? bid : bid-4096)*256 + threadIdx.x;  // float4 idx
  const float4* P4 = (const float4*)(condside ? Pc : Pr);
  float4 a = P4[idx];
  float4 b = P4[idx + 1048576];
  float4 o;
  o.x = a.x + b.x; o.y = a.y + b.y; o.z = a.z + b.z; o.w = a.w + b.w;
  if (condside){
    float4 c = P4[idx + 2097152];
    o.x += c.x; o.y += c.y; o.z += c.z; o.w += c.w;
  }
  const int nlin = idx*4;
  const int m = nlin >> 10, n = nlin & 1023;
  u16* dst = condside ? cond : refv;
  union { uint2 u; u16 s[4]; } ov;
  ov.s[0] = f2bf(o.x); ov.s[1] = f2bf(o.y);
  ov.s[2] = f2bf(o.z); ov.s[3] = f2bf(o.w);
  *(uint2*)&dst[((size_t)((m>>10)*HEADS + (n>>7))*NSEQ + (m&1023))*DHEAD + (n&127)] = ov.u;
}

// ---------------- MFMA GEMM: dbuf + global_load_lds, conflict-free LDS ------
// (steps 4 and 7)  Template BK = K-tile depth (32 or 64).
template<int BK>
__global__ __launch_bounds__(256)
void gemm_kernel(const u16* __restrict__ A0, const u16* __restrict__ A1,
                 const u16* __restrict__ A2, const u16* __restrict__ A0b,
                 const u16* __restrict__ A1b,
                 const u16* __restrict__ B1, const u16* __restrict__ B2,
                 void* __restrict__ Cv, void* __restrict__ Cv2,
                 const float* __restrict__ bias,
                 int K1, int K2, int lda, int ldb1, int ldb2, int ldc,
                 long a_plane, long b_plane, long c_plane,
                 int epi1, int epi2, int z_split, float alpha)
{
  constexpr int SUBS = BK/32;
  __shared__ __attribute__((aligned(16))) u16 sA[2][SUBS*4096];
  __shared__ __attribute__((aligned(16))) u16 sB[2][SUBS*4096];
  const int t = threadIdx.x;
  const int m0 = blockIdx.y*128, n0 = blockIdx.x*128;
  const int zz = blockIdx.z;
  const bool side = (zz >= z_split);
  const int z = side ? (zz - z_split) : zz;
  const u16* a0 = (side ? A0b : A0) + (size_t)z*a_plane;
  const u16* a1 = (side ? A1b : A1) + (size_t)z*a_plane;
  const u16* a2 = A2 + (size_t)z*a_plane;
  const u16* bB = (side ? B2 : B1) + (size_t)z*b_plane;
  void* Cp = side ? Cv2 : Cv;
  const int EPI = side ? epi2 : epi1;
  const int K   = side ? K2 : K1;
  const int ldb = side ? ldb2 : ldb1;

  const int wave = t>>6, lane = t&63;
  const int wm = (wave>>1)*64, wn = (wave&1)*64;
  const int lm = lane&15, q = lane>>4;

  const f32x4 zero4 = {0.f,0.f,0.f,0.f};
  f32x4 acc[4][4];
#pragma unroll
  for (int i=0;i<4;i++)
#pragma unroll
    for (int j=0;j<4;j++) acc[i][j] = zero4;

  const int arowblk = wave*32;

  const int KT = K / BK;

  auto issueA = [&](int kt, int buf){
    const int kg = kt*BK, seg = kg>>10, ka = kg&1023;
    const u16* Ap = (seg==0) ? a0 : (seg==1 ? a1 : a2);
#pragma unroll
    for (int sub=0; sub<SUBS; ++sub)
#pragma unroll
      for (int rr=0; rr<2; ++rr){
        const int rb = arowblk + rr*16;
        gload_lds16(Ap + (size_t)(m0+rb+lm)*lda + (ka + sub*32 + q*8),
                    &sA[buf][sub*4096 + rb*32]);
      }
  };
  auto issueB = [&](int kt, int buf){
    const int kg = kt*BK;
#pragma unroll
    for (int sub=0; sub<SUBS; ++sub)
#pragma unroll
      for (int rr=0; rr<2; ++rr){
        const int rb = arowblk + rr*16;
        gload_lds16(bB + (size_t)(n0+rb+lm)*ldb + (kg + sub*32 + q*8),
                    &sB[buf][sub*4096 + rb*32]);
      }
  };

  issueA(0, 0);
  issueB(0, 0);

  int cur = 0;
  for (int kt=0; kt<KT; ++kt){
    __syncthreads();
    if (kt+1 < KT){
      issueA(kt+1, cur^1);
      issueB(kt+1, cur^1);
    }
#pragma unroll
    for (int sub=0; sub<SUBS; ++sub){
      bf16x8 af[4], bfr[4];
#pragma unroll
      for (int f=0; f<4; ++f){
        af[f]  = *(const bf16x8*)&sA[cur][sub*4096 + ((wm>>4)+f)*512 + lane*8];
        bfr[f] = *(const bf16x8*)&sB[cur][sub*4096 + ((wn>>4)+f)*512 + lane*8];
      }
#pragma unroll
      for (int fm=0; fm<4; ++fm)
#pragma unroll
        for (int fn=0; fn<4; ++fn)
          acc[fm][fn] = __builtin_amdgcn_mfma_f32_16x16x32_bf16(af[fm], bfr[fn], acc[fm][fn], 0, 0, 0);
    }
    cur ^= 1;
  }

#pragma unroll
  for (int fm=0; fm<4; ++fm){
#pragma unroll
    for (int fn=0; fn<4; ++fn){
#pragma unroll
      for (int r=0; r<4; ++r){
        const int m = m0 + wm + fm*16 + q*4 + r;
        const int n = n0 + wn + fn*16 + lm;
        float val = acc[fm][fn][r] * alpha;
        if (EPI == 0){
          ((u16*)Cp)[(size_t)z*c_plane + (size_t)m*ldc + n] = f2bf(val);
        } else if (EPI == 1){
          ((u16*)Cp)[((size_t)(z>>3)*NSEQ + m)*DIM + (size_t)(z&7)*DHEAD + n] = f2bf(val);
        } else if (EPI == 2){
          ((float*)Cp)[(size_t)m*ldc + n] = val + bias[n];
        } else if (EPI == 3){
          ((u16*)Cp)[(size_t)(((m>>10)*HEADS + (n>>7))*NSEQ + (m&1023))*DHEAD + (n&127)] = f2bf(val);
        } else {
          ((float*)Cp)[((size_t)(z>>3)*NSEQ + m)*DIM + (size_t)(z&7)*DHEAD + n] = val;
        }
      }
    }
  }
}

// ------- split-K final projection: out_pre[4096,1024] @ WoT -> partials -----
__global__ __launch_bounds__(256)
void gemm8_kernel(const u16* __restrict__ A, const u16* __restrict__ B,
                  float* __restrict__ P)
{
  __shared__ __attribute__((aligned(16))) u16 sA[2][4096];
  __shared__ __attribute__((aligned(16))) u16 sB[2][4096];
  const int t = threadIdx.x;
  const int bid = blockIdx.x;
  const int w = (bid & 7)*128 + (bid >> 3);
  const int x = w & 7;          // N tile (0..7)
  const int y = (w >> 3) & 31;  // M tile (0..31)
  const int s = w >> 8;         // K slice (0..3)
  const int m0 = y*128, n0 = x*128, k0 = s*256;

  const int wave = t>>6, lane = t&63;
  const int wm = (wave>>1)*64, wn = (wave&1)*64;
  const int lm = lane&15, q = lane>>4;

  const f32x4 zero4 = {0.f,0.f,0.f,0.f};
  f32x4 acc[4][4];
#pragma unroll
  for (int i=0;i<4;i++)
#pragma unroll
    for (int j=0;j<4;j++) acc[i][j] = zero4;

  const int arowblk = wave*32;

  auto issueA = [&](int kt, int buf){
    const int kg = k0 + (kt<<5);
#pragma unroll
    for (int rr=0; rr<2; ++rr){
      const int rb = arowblk + rr*16;
      gload_lds16(A + (size_t)(m0+rb+lm)*1024 + (kg + q*8), &sA[buf][rb*32]);
    }
  };
  auto issueB = [&](int kt, int buf){
    const int kg = k0 + (kt<<5);
#pragma unroll
    for (int rr=0; rr<2; ++rr){
      const int rb = arowblk + rr*16;
      gload_lds16(B + (size_t)(n0+rb+lm)*1024 + (kg + q*8), &sB[buf][rb*32]);
    }
  };

  issueA(0, 0); issueB(0, 0);

  int cur = 0;
  for (int kt=0; kt<8; ++kt){
    __syncthreads();
    if (kt+1 < 8){
      issueA(kt+1, cur^1);
      issueB(kt+1, cur^1);
    }
    bf16x8 af[4], bfr[4];
#pragma unroll
    for (int f=0; f<4; ++f){
      af[f]  = *(const bf16x8*)&sA[cur][((wm>>4)+f)*512 + lane*8];
      bfr[f] = *(const bf16x8*)&sB[cur][((wn>>4)+f)*512 + lane*8];
    }
#pragma unroll
    for (int fm=0; fm<4; ++fm)
#pragma unroll
      for (int fn=0; fn<4; ++fn)
        acc[fm][fn] = __builtin_amdgcn_mfma_f32_16x16x32_bf16(af[fm], bfr[fn], acc[fm][fn], 0, 0, 0);
    cur ^= 1;
  }

  float* Pp = P + (size_t)s*4194304;   // 4096*1024 per slice
#pragma unroll
  for (int fm=0; fm<4; ++fm){
#pragma unroll
    for (int fn=0; fn<4; ++fn){
#pragma unroll
      for (int r=0; r<4; ++r){
        const int m = m0 + wm + fm*16 + q*4 + r;
        const int n = n0 + wn + fn*16 + lm;
        Pp[(size_t)m*1024 + n] = acc[fm][fn][r];
      }
    }
  }
}

// ------- reduce 4 fp32 partial planes + bias -> out (fp32) ------------------
__global__ __launch_bounds__(256)
void red8_kernel(const float* __restrict__ P, const float* __restrict__ bias,
                 float* __restrict__ out)
{
  const int idx = blockIdx.x*256 + threadIdx.x;   // float4 index, 1M total
  const float4* P4 = (const float4*)P;
  float4 a = P4[idx];
  float4 b = P4[idx + 1048576];
  float4 c = P4[idx + 2097152];
  float4 d = P4[idx + 3145728];
  float4 bb = ((const float4*)bias)[idx & 255];
  float4 o;
  o.x = a.x + b.x + c.x + d.x + bb.x;
  o.y = a.y + b.y + c.y + d.y + bb.y;
  o.z = a.z + b.z + c.z + d.z + bb.z;
  o.w = a.w + b.w + c.w + d.w + bb.w;
  ((float4*)out)[idx] = o;
}

// ------- transpose both operands: [32][1024][128] -> [32][128][1024] --------
__global__ __launch_bounds__(256)
void transpose2_kernel(const u16* __restrict__ cond, const u16* __restrict__ refv,
                       u16* __restrict__ condT, u16* __restrict__ refvT)
{
  __shared__ u16 tile[32][33];
  const int zz = blockIdx.z;
  const u16* X = (zz < 32) ? cond : refv;
  u16* XT      = (zz < 32) ? condT : refvT;
  const int z = zz & 31;
  const int i0 = blockIdx.y*32, d0 = blockIdx.x*32;
  const int t = threadIdx.x;
  const int tc = t & 31, tr = t >> 5;
  const u16* Xp = X + (size_t)z*NSEQ*DHEAD;
#pragma unroll
  for (int p=0;p<4;p++){
    int i = tr + p*8;
    tile[i][tc] = Xp[(size_t)(i0+i)*DHEAD + d0 + tc];
  }
  __syncthreads();
  u16* Op = XT + (size_t)z*DHEAD*NSEQ;
#pragma unroll
  for (int p=0;p<4;p++){
    int d = tr + p*8;
    Op[(size_t)(d0+d)*NSEQ + i0 + tc] = tile[tc][d];
  }
}

// ---------------- softmax stats: row + col fused in one launch ---------------
__global__ __launch_bounds__(256)
void stats_kernel(const u16* __restrict__ sim,
                  float* __restrict__ rmax, float* __restrict__ rrcp,
                  float* __restrict__ cmax, float* __restrict__ crcp)
{
  __shared__ float smx[4][64], ssm[4][64];
  if (blockIdx.x < 8192){
    const int wave = threadIdx.x >> 6, lane = threadIdx.x & 63;
    const int row = blockIdx.x*4 + wave;   // (b*8+h)*1024+i
    const u16* sr = sim + (size_t)row * NSEQ;
    float v[16]; float m = -1e30f;
#pragma unroll
    for (int c=0;c<16;c++){ v[c] = bf2f(sr[lane + c*64]); m = fmaxf(m, v[c]); }
#pragma unroll
    for (int off=32; off; off>>=1) m = fmaxf(m, __shfl_xor(m, off));
    float s = 0.f;
#pragma unroll
    for (int c=0;c<16;c++) s += __expf(v[c]-m);
#pragma unroll
    for (int off=32; off; off>>=1) s += __shfl_xor(s, off);
    if (lane == 0){ rmax[row] = m; rrcp[row] = 1.0f/s; }
  } else {
    const int t = threadIdx.x;
    const int jl = t & 63, slice = t >> 6;
    const int c = (blockIdx.x - 8192)*64 + jl;   // (b*8+h)*1024 + j
    const int bh = c >> 10, j = c & 1023;
    const u16* sp = sim + (size_t)bh*NSEQ*NSEQ + j + (size_t)(slice*256)*NSEQ;
    float m0=-1e30f, m1=-1e30f, m2=-1e30f, m3=-1e30f;
    for (int i=0;i<256;i+=4){
      m0 = fmaxf(m0, bf2f(sp[(size_t)(i  )*NSEQ]));
      m1 = fmaxf(m1, bf2f(sp[(size_t)(i+1)*NSEQ]));
      m2 = fmaxf(m2, bf2f(sp[(size_t)(i+2)*NSEQ]));
      m3 = fmaxf(m3, bf2f(sp[(size_t)(i+3)*NSEQ]));
    }
    smx[slice][jl] = fmaxf(fmaxf(m0,m1), fmaxf(m2,m3));
    __syncthreads();
    const float M = fmaxf(fmaxf(smx[0][jl], smx[1][jl]),
                          fmaxf(smx[2][jl], smx[3][jl]));
    float s0=0.f, s1=0.f, s2=0.f, s3=0.f;
    for (int i=0;i<256;i+=4){
      s0 += __expf(bf2f(sp[(size_t)(i  )*NSEQ]) - M);
      s1 += __expf(bf2f(sp[(size_t)(i+1)*NSEQ]) - M);
      s2 += __expf(bf2f(sp[(size_t)(i+2)*NSEQ]) - M);
      s3 += __expf(bf2f(sp[(size_t)(i+3)*NSEQ]) - M);
    }
    ssm[slice][jl] = s0+s1+s2+s3;
    __syncthreads();
    if (slice == 0){
      float S = ssm[0][jl] + ssm[1][jl] + ssm[2][jl] + ssm[3][jl];
      cmax[c] = M; crcp[c] = 1.0f/S;
    }
  }
}

// ---------------- softmax + talking-heads mix ----------------
__global__ __launch_bounds__(256)
void mix_kernel(u16* simam,
                const float* __restrict__ rmax, const float* __restrict__ rrcp,
                const float* __restrict__ cmax, const float* __restrict__ crcp,
                const float* __restrict__ thw, const float* __restrict__ cthw,
                u16* __restrict__ cmT)
{
  __shared__ float s_th[64], s_cth[64];
  __shared__ u16 s_cm[8][32][33];
  const int t = threadIdx.x;
  if (t < 64){ s_th[t] = thw[t]; s_cth[t] = cthw[t]; }
  __syncthreads();
  const int b = blockIdx.z, i0 = blockIdx.y*32, j0 = blockIdx.x*32;
  const int tj = t & 31, ti = t >> 5;
  for (int p=0;p<4;p++){
    const int i = ti + p*8;
    float a[8], c[8];
#pragma unroll
    for (int h=0;h<8;h++){
      const int bh = b*8 + h;
      const float v = bf2f(simam[((size_t)bh*NSEQ + (i0+i))*NSEQ + j0 + tj]);
      a[h] = __expf(v - rmax[(size_t)bh*NSEQ + i0+i]) * rrcp[(size_t)bh*NSEQ + i0+i];
      c[h] = __expf(v - cmax[(size_t)bh*NSEQ + j0+tj]) * crcp[(size_t)bh*NSEQ + j0+tj];
    }
#pragma unroll
    for (int g=0;g<8;g++){
      float sa = 0.f, sc = 0.f;
#pragma unroll
      for (int h=0;h<8;h++){ sa += s_th[g*8+h]*a[h]; sc += s_cth[g*8+h]*c[h]; }
      simam[((size_t)(b*8+g)*NSEQ + (i0+i))*NSEQ + j0 + tj] = f2bf(sa);
      s_cm[g][i][tj] = f2bf(sc);
    }
  }
  __syncthreads();
#pragma unroll
  for (int g=0;g<8;g++){
#pragma unroll
    for (int p=0;p<4;p++){
      const int j = ti + p*8;
      cmT[((size_t)(b*8+g)*NSEQ + (j0+j))*NSEQ + i0 + tj] = s_cm[g][tj][j];
    }
  }
}

extern "C" void kernel_launch(void* const* d_in, const int* in_sizes, int n_in,
                              void* d_out, int out_size, void* d_ws, size_t ws_size,
                              hipStream_t stream)
{
  const float* x     = (const float*)d_in[0];
  const float* cinfo = (const float*)d_in[1];
  const float* ref   = (const float*)d_in[2];
  const float* ln_w  = (const float*)d_in[3];
  const float* ln_b  = (const float*)d_in[4];
  const float* cln_w = (const float*)d_in[5];
  const float* cln_b = (const float*)d_in[6];
  const float* Wk    = (const float*)d_in[7];
  const float* Wv    = (const float*)d_in[8];
  const float* Wo    = (const float*)d_in[9];
  const float* bo    = (const float*)d_in[10];
  const float* thw   = (const float*)d_in[11];
  const float* cthw  = (const float*)d_in[12];
  float* out = (float*)d_out;

  char* ws = (char*)d_ws;
  u16* xn    = (u16*)(ws + 0);          // 8 MB; reused as out_pre
  u16* cn    = (u16*)(ws + 8388608);    // 8 MB; reused for softmax stats
  u16* rn    = (u16*)(ws + 16777216);   // 8 MB
  u16* cond  = (u16*)(ws + 25165824);   // 8 MB  [b,h,i,d]
  u16* refv  = (u16*)(ws + 33554432);   // 8 MB  [b,h,j,d]
  u16* condT = (u16*)(ws + 41943040);   // 8 MB  [b,h,d,j]
  u16* refvT = (u16*)(ws + 50331648);   // 8 MB  [b,h,d,j]
  u16* sim   = (u16*)(ws + 58720256);   // 64 MB [b,h,i,j]; holds step-2 cond
                                        //        partials first, then sim/am,
                                        //        then step-8 fp32 partials
  u16* cmT   = (u16*)(ws + 125829120);  // 64 MB [b,g,j,i]; holds step-2 refv
                                        //        partials first
  u16* WkT   = (u16*)(ws + 192937984);  // 6 MB  [1024,3072] bf16
  u16* WvT   = (u16*)(ws + 199229440);  // 4 MB  [1024,2048] bf16
  u16* WoT   = (u16*)(ws + 203423744);  // 2 MB  [1024,1024] bf16
  float* rmax = (float*)(ws + 8388608);
  float* rrcp = (float*)(ws + 8388608 + 131072);
  float* cmax = (float*)(ws + 8388608 + 262144);
  float* crcp = (float*)(ws + 8388608 + 393216);
  u16* out_pre = (u16*)(ws + 0);

  // 1) LayerNorms (fp32 -> bf16), all three in one launch
  ln3_kernel<<<dim3(4096,3), 256, 0, stream>>>(x, ref, cinfo, ln_w, ln_b,
                                               cln_w, cln_b, xn, rn, cn);

  // 1b) weight convert+transpose fp32[K,N] -> bf16[N,K]
  wcvt_kernel<<<dim3(96,32,3), 256, 0, stream>>>(Wk, Wv, Wo, WkT, WvT, WoT);

  // 2) fused projections, split-K (slices aligned to A segments):
  //    1280 blocks = 5 blk/CU (32KB LDS). Partials: cond -> sim region (48MB),
  //    refv -> cmT region (32MB). Then reduce + head-split bf16 store.
  gemmsk2_kernel<<<1280, 256, 0, stream>>>(xn, cn, rn, WkT, WvT,
                                           (float*)sim, (float*)cmT);
  redsk2_kernel<<<8192, 256, 0, stream>>>((const float*)sim, (const float*)cmT,
                                          cond, refv);

  // 3) transposed copies for the PV/context GEMM B-operands (one launch)
  transpose2_kernel<<<dim3(4,32,64), 256, 0, stream>>>(cond, refv, condT, refvT);

  // 4) sim = cond @ refv^T * scale  (per (b,h) plane; 2048 blocks, BK=32)
  gemm_kernel<32><<<dim3(8,8,32), 256, 0, stream>>>(
      cond, cond, cond, cond, cond, refv, refv, sim, sim, nullptr,
      DHEAD, DHEAD, DHEAD, DHEAD, DHEAD, NSEQ,
      (long)NSEQ*DHEAD, (long)NSEQ*DHEAD, (long)NSEQ*NSEQ, 0, 0, 1000000, ATT_SCALE);

  // 5) softmax stats (row + col in one launch; col is 2-pass max/sum)
  stats_kernel<<<8704, 256, 0, stream>>>(sim, rmax, rrcp, cmax, crcp);

  // 6) both softmaxes + talking heads (am in-place over sim; cmT transposed)
  mix_kernel<<<dim3(32,32,4), 256, 0, stream>>>(sim, rmax, rrcp, cmax, crcp, thw, cthw, cmT);

  // 7) fused (BK=64): z<32: am@refvT -> out_pre (bf16 head-merge);
  //    z>=32: cmT@condT -> ctx out (fp32)
  gemm_kernel<64><<<dim3(1,8,64), 256, 0, stream>>>(
      sim, sim, sim, cmT, cmT, refvT, condT, out_pre, out + (size_t)BATCH*NSEQ*DIM, nullptr,
      1024, 1024, NSEQ, NSEQ, NSEQ, 0,
      (long)NSEQ*NSEQ, (long)DHEAD*NSEQ, 0, 1, 4, 32, 1.0f);

  // 8) final projection, split-K=4 + chunked XCD swizzle: partials into sim
  //    region (dead after step 7), then deterministic reduce + bias.
  gemm8_kernel<<<1024, 256, 0, stream>>>(out_pre, WoT, (float*)sim);
  red8_kernel<<<4096, 256, 0, stream>>>((const float*)sim, bo, out);
}

// Round 9
// 447.374 us; speedup vs baseline: 1.3279x; 1.1734x over previous
//
#include <hip/hip_runtime.h>
#include <hip/hip_bf16.h>
#include <stdint.h>

typedef unsigned short u16;
typedef __attribute__((ext_vector_type(8))) short bf16x8;
typedef __attribute__((ext_vector_type(4))) float f32x4;

#define HEADS 8
#define DHEAD 128
#define NSEQ 1024
#define BATCH 4
#define DIM 1024
#define ATT_SCALE 0.088388347648318447f  // 1/sqrt(128)

static __device__ __forceinline__ float bf2f(u16 u){
  union { unsigned int i; float f; } c; c.i = ((unsigned int)u) << 16; return c.f;
}
static __device__ __forceinline__ u16 f2bf(float f){
  union { float f; unsigned int i; } c; c.f = f;
  unsigned int x = c.i;
  return (u16)((x + 0x7fffu + ((x >> 16) & 1u)) >> 16);
}

// async global->LDS, 16B per lane, dest = wave-uniform base + lane*16
static __device__ __forceinline__ void gload_lds16(const void* g, void* l){
  __builtin_amdgcn_global_load_lds((__attribute__((address_space(1))) void*)(g),
                                   (__attribute__((address_space(3))) void*)(l),
                                   16, 0, 0);
}

// ---------------- LayerNorm x3 fused: fp32 in, bf16 out ---------------------
// grid (4096, 3): y=0 x->xn (ln), y=1 ref->rn (ln), y=2 cinfo->cn (cln)
__global__ __launch_bounds__(256)
void ln3_kernel(const float* __restrict__ x, const float* __restrict__ ref,
                const float* __restrict__ cinfo,
                const float* __restrict__ ln_w, const float* __restrict__ ln_b,
                const float* __restrict__ cln_w, const float* __restrict__ cln_b,
                u16* __restrict__ xn, u16* __restrict__ rn, u16* __restrict__ cn)
{
  const int z = blockIdx.y;
  const float* src = (z==0) ? x : (z==1) ? ref : cinfo;
  const float* w   = (z==2) ? cln_w : ln_w;
  const float* b   = (z==2) ? cln_b : ln_b;
  u16* out         = (z==0) ? xn : (z==1) ? rn : cn;

  const int row = blockIdx.x;
  const int t = threadIdx.x;
  const float* xr = src + (size_t)row * DIM;
  float4 v4 = *(const float4*)(xr + t*4);
  float v[4] = {v4.x, v4.y, v4.z, v4.w};
  float s = v[0]+v[1]+v[2]+v[3];
  __shared__ float red[256];
  red[t] = s; __syncthreads();
  for (int o=128;o;o>>=1){ if (t<o) red[t]+=red[t+o]; __syncthreads(); }
  const float mean = red[0] * (1.0f/DIM);
  __syncthreads();
  s = 0.f;
#pragma unroll
  for (int i=0;i<4;i++){ float d = v[i]-mean; s += d*d; }
  red[t] = s; __syncthreads();
  for (int o=128;o;o>>=1){ if (t<o) red[t]+=red[t+o]; __syncthreads(); }
  const float rstd = rsqrtf(red[0]*(1.0f/DIM) + 1e-5f);
  float4 w4 = *(const float4*)(w + t*4);
  float4 b4 = *(const float4*)(b + t*4);
  float wv[4] = {w4.x, w4.y, w4.z, w4.w};
  float bv[4] = {b4.x, b4.y, b4.z, b4.w};
  union { uint2 u; u16 s[4]; } ov;
#pragma unroll
  for (int i=0;i<4;i++)
    ov.s[i] = f2bf((v[i]-mean)*rstd*wv[i] + bv[i]);
  *(uint2*)(out + (size_t)row*DIM + t*4) = ov.u;
}

// -------- weight convert+transpose: fp32 [K,1024] -> bf16 [1024,K] ----------
__global__ __launch_bounds__(256)
void wcvt_kernel(const float* __restrict__ Wk, const float* __restrict__ Wv,
                 const float* __restrict__ Wo,
                 u16* __restrict__ WkT, u16* __restrict__ WvT, u16* __restrict__ WoT)
{
  const int z = blockIdx.z;
  const int K = (z==0) ? 3072 : (z==1) ? 2048 : 1024;
  if ((int)blockIdx.x*32 >= K) return;
  const float* W = (z==0) ? Wk : (z==1) ? Wv : Wo;
  u16* WT = (z==0) ? WkT : (z==1) ? WvT : WoT;
  __shared__ float tile[32][33];
  const int k0 = blockIdx.x*32, n0 = blockIdx.y*32;
  const int t = threadIdx.x, tc = t&31, tr = t>>5;
#pragma unroll
  for (int p=0;p<4;p++)
    tile[tr+p*8][tc] = W[(size_t)(k0+tr+p*8)*DIM + n0+tc];
  __syncthreads();
#pragma unroll
  for (int p=0;p<4;p++)
    WT[(size_t)(n0+tr+p*8)*K + k0+tc] = f2bf(tile[tc][tr+p*8]);
}

// ---------------- MFMA GEMM: dbuf + global_load_lds, conflict-free LDS ------
// C[M,N] = sum_k A[m,k]*B[k,n]. A bf16 K-major, <=3 segments of 1024 cols.
// B is bf16 BT [N,K] row-major (K-major operand). Dual-problem via z_split.
// Template BK = K-tile depth (32 or 64). BK=64 halves barriers per unit K.
// LDS layout per 32-k sub-tile: 8 blocks of 16 rows; slot l (16B) of block g
// holds [row=g*16+(l&15)][k-oct=l>>4] -> ds_read_b128 conflict-free.
// epi: 0 bf16 C[z*cp+m*ldc+n]*alpha | 1 bf16 head-merge | 2 fp32 +bias[n]
//      3 bf16 head-split | 4 fp32 head-merge
template<int BK>
__global__ __launch_bounds__(256)
void gemm_kernel(const u16* __restrict__ A0, const u16* __restrict__ A1,
                 const u16* __restrict__ A2, const u16* __restrict__ A0b,
                 const u16* __restrict__ A1b,
                 const u16* __restrict__ B1, const u16* __restrict__ B2,
                 void* __restrict__ Cv, void* __restrict__ Cv2,
                 const float* __restrict__ bias,
                 int K1, int K2, int lda, int ldb1, int ldb2, int ldc,
                 long a_plane, long b_plane, long c_plane,
                 int epi1, int epi2, int z_split, float alpha)
{
  constexpr int SUBS = BK/32;
  __shared__ __attribute__((aligned(16))) u16 sA[2][SUBS*4096];
  __shared__ __attribute__((aligned(16))) u16 sB[2][SUBS*4096];
  const int t = threadIdx.x;
  const int m0 = blockIdx.y*128, n0 = blockIdx.x*128;
  const int zz = blockIdx.z;
  const bool side = (zz >= z_split);
  const int z = side ? (zz - z_split) : zz;
  const u16* a0 = (side ? A0b : A0) + (size_t)z*a_plane;
  const u16* a1 = (side ? A1b : A1) + (size_t)z*a_plane;
  const u16* a2 = A2 + (size_t)z*a_plane;
  const u16* bB = (side ? B2 : B1) + (size_t)z*b_plane;
  void* Cp = side ? Cv2 : Cv;
  const int EPI = side ? epi2 : epi1;
  const int K   = side ? K2 : K1;
  const int ldb = side ? ldb2 : ldb1;

  const int wave = t>>6, lane = t&63;
  const int wm = (wave>>1)*64, wn = (wave&1)*64;
  const int lm = lane&15, q = lane>>4;

  const f32x4 zero4 = {0.f,0.f,0.f,0.f};
  f32x4 acc[4][4];
#pragma unroll
  for (int i=0;i<4;i++)
#pragma unroll
    for (int j=0;j<4;j++) acc[i][j] = zero4;

  const int arowblk = wave*32;

  const int KT = K / BK;

  auto issueA = [&](int kt, int buf){
    const int kg = kt*BK, seg = kg>>10, ka = kg&1023;
    const u16* Ap = (seg==0) ? a0 : (seg==1 ? a1 : a2);
#pragma unroll
    for (int sub=0; sub<SUBS; ++sub)
#pragma unroll
      for (int rr=0; rr<2; ++rr){
        const int rb = arowblk + rr*16;
        gload_lds16(Ap + (size_t)(m0+rb+lm)*lda + (ka + sub*32 + q*8),
                    &sA[buf][sub*4096 + rb*32]);
      }
  };
  auto issueB = [&](int kt, int buf){
    const int kg = kt*BK;
#pragma unroll
    for (int sub=0; sub<SUBS; ++sub)
#pragma unroll
      for (int rr=0; rr<2; ++rr){
        const int rb = arowblk + rr*16;
        gload_lds16(bB + (size_t)(n0+rb+lm)*ldb + (kg + sub*32 + q*8),
                    &sB[buf][sub*4096 + rb*32]);
      }
  };

  issueA(0, 0);
  issueB(0, 0);

  int cur = 0;
  for (int kt=0; kt<KT; ++kt){
    __syncthreads();
    if (kt+1 < KT){
      issueA(kt+1, cur^1);
      issueB(kt+1, cur^1);
    }
#pragma unroll
    for (int sub=0; sub<SUBS; ++sub){
      bf16x8 af[4], bfr[4];
#pragma unroll
      for (int f=0; f<4; ++f){
        af[f]  = *(const bf16x8*)&sA[cur][sub*4096 + ((wm>>4)+f)*512 + lane*8];
        bfr[f] = *(const bf16x8*)&sB[cur][sub*4096 + ((wn>>4)+f)*512 + lane*8];
      }
#pragma unroll
      for (int fm=0; fm<4; ++fm)
#pragma unroll
        for (int fn=0; fn<4; ++fn)
          acc[fm][fn] = __builtin_amdgcn_mfma_f32_16x16x32_bf16(af[fm], bfr[fn], acc[fm][fn], 0, 0, 0);
    }
    cur ^= 1;
  }

#pragma unroll
  for (int fm=0; fm<4; ++fm){
#pragma unroll
    for (int fn=0; fn<4; ++fn){
#pragma unroll
      for (int r=0; r<4; ++r){
        const int m = m0 + wm + fm*16 + q*4 + r;
        const int n = n0 + wn + fn*16 + lm;
        float val = acc[fm][fn][r] * alpha;
        if (EPI == 0){
          ((u16*)Cp)[(size_t)z*c_plane + (size_t)m*ldc + n] = f2bf(val);
        } else if (EPI == 1){
          ((u16*)Cp)[((size_t)(z>>3)*NSEQ + m)*DIM + (size_t)(z&7)*DHEAD + n] = f2bf(val);
        } else if (EPI == 2){
          ((float*)Cp)[(size_t)m*ldc + n] = val + bias[n];
        } else if (EPI == 3){
          ((u16*)Cp)[(size_t)(((m>>10)*HEADS + (n>>7))*NSEQ + (m&1023))*DHEAD + (n&127)] = f2bf(val);
        } else {
          ((float*)Cp)[((size_t)(z>>3)*NSEQ + m)*DIM + (size_t)(z&7)*DHEAD + n] = val;
        }
      }
    }
  }
}

// -------- sim GEMM + fused softmax partial stats (replaces step 4 + stats) --
// sim = cond @ refv^T * ATT_SCALE per (b,h) plane. Identical K-loop to
// gemm_kernel<32> (K=128, KT=4). Epilogue: store bf16 sim AND per-block
// row/col partial (max, sumexp) computed from the bf16-ROUNDED values
// (matches old read-back semantics). Partials indexed by 16 column-groups
// (xg = bx*2 + wn/64) for rows, 16 row-groups (yg = by*2 + wm/64) for cols.
__global__ __launch_bounds__(256)
void gemmqk_kernel(const u16* __restrict__ cond, const u16* __restrict__ refv,
                   u16* __restrict__ sim,
                   float* __restrict__ RP, float* __restrict__ RS,
                   float* __restrict__ CP, float* __restrict__ CS)
{
  __shared__ __attribute__((aligned(16))) u16 sA[2][4096];
  __shared__ __attribute__((aligned(16))) u16 sB[2][4096];
  const int t = threadIdx.x;
  const int m0 = blockIdx.y*128, n0 = blockIdx.x*128;
  const int z = blockIdx.z;
  const u16* A = cond + (size_t)z*NSEQ*DHEAD;
  const u16* B = refv + (size_t)z*NSEQ*DHEAD;

  const int wave = t>>6, lane = t&63;
  const int wm = (wave>>1)*64, wn = (wave&1)*64;
  const int lm = lane&15, q = lane>>4;

  const f32x4 zero4 = {0.f,0.f,0.f,0.f};
  f32x4 acc[4][4];
#pragma unroll
  for (int i=0;i<4;i++)
#pragma unroll
    for (int j=0;j<4;j++) acc[i][j] = zero4;

  const int arowblk = wave*32;

  auto issueA = [&](int kt, int buf){
    const int kg = kt<<5;
#pragma unroll
    for (int rr=0; rr<2; ++rr){
      const int rb = arowblk + rr*16;
      gload_lds16(A + (size_t)(m0+rb+lm)*DHEAD + (kg + q*8), &sA[buf][rb*32]);
    }
  };
  auto issueB = [&](int kt, int buf){
    const int kg = kt<<5;
#pragma unroll
    for (int rr=0; rr<2; ++rr){
      const int rb = arowblk + rr*16;
      gload_lds16(B + (size_t)(n0+rb+lm)*DHEAD + (kg + q*8), &sB[buf][rb*32]);
    }
  };

  issueA(0, 0); issueB(0, 0);

  int cur = 0;
  for (int kt=0; kt<4; ++kt){                 // K=128, BK=32
    __syncthreads();
    if (kt+1 < 4){
      issueA(kt+1, cur^1);
      issueB(kt+1, cur^1);
    }
    bf16x8 af[4], bfr[4];
#pragma unroll
    for (int f=0; f<4; ++f){
      af[f]  = *(const bf16x8*)&sA[cur][((wm>>4)+f)*512 + lane*8];
      bfr[f] = *(const bf16x8*)&sB[cur][((wn>>4)+f)*512 + lane*8];
    }
#pragma unroll
    for (int fm=0; fm<4; ++fm)
#pragma unroll
      for (int fn=0; fn<4; ++fn)
        acc[fm][fn] = __builtin_amdgcn_mfma_f32_16x16x32_bf16(af[fm], bfr[fn], acc[fm][fn], 0, 0, 0);
    cur ^= 1;
  }

  // epilogue: store bf16 sim; keep bf16-rounded fp32 values in acc
#pragma unroll
  for (int fm=0; fm<4; ++fm){
#pragma unroll
    for (int fn=0; fn<4; ++fn){
#pragma unroll
      for (int r=0; r<4; ++r){
        const int m = m0 + wm + fm*16 + q*4 + r;
        const int n = n0 + wn + fn*16 + lm;
        const u16 bv = f2bf(acc[fm][fn][r] * ATT_SCALE);
        sim[((size_t)z*NSEQ + m)*NSEQ + n] = bv;
        acc[fm][fn][r] = bf2f(bv);
      }
    }
  }

  // row partials: row m = m0+wm+fm*16+q*4+r spans lm(16 lanes) x fn(4 in-thread)
  const int xg = blockIdx.x*2 + (wn>>6);
#pragma unroll
  for (int fm=0; fm<4; ++fm){
#pragma unroll
    for (int r=0; r<4; ++r){
      float rm = fmaxf(fmaxf(acc[fm][0][r], acc[fm][1][r]),
                       fmaxf(acc[fm][2][r], acc[fm][3][r]));
#pragma unroll
      for (int msk=1; msk<16; msk<<=1) rm = fmaxf(rm, __shfl_xor(rm, msk));
      float rs = __expf(acc[fm][0][r]-rm) + __expf(acc[fm][1][r]-rm)
               + __expf(acc[fm][2][r]-rm) + __expf(acc[fm][3][r]-rm);
#pragma unroll
      for (int msk=1; msk<16; msk<<=1) rs += __shfl_xor(rs, msk);
      if (lm == 0){
        const int m = m0 + wm + fm*16 + q*4 + r;
        RP[((size_t)z*NSEQ + m)*16 + xg] = rm;
        RS[((size_t)z*NSEQ + m)*16 + xg] = rs;
      }
    }
  }

  // col partials: col n = n0+wn+fn*16+lm spans q(4 lanes) x fm,r(16 in-thread)
  const int yg = blockIdx.y*2 + (wm>>6);
#pragma unroll
  for (int fn=0; fn<4; ++fn){
    float cm = -1e30f;
#pragma unroll
    for (int fm=0; fm<4; ++fm)
#pragma unroll
      for (int r=0; r<4; ++r) cm = fmaxf(cm, acc[fm][fn][r]);
    cm = fmaxf(cm, __shfl_xor(cm, 16));
    cm = fmaxf(cm, __shfl_xor(cm, 32));
    float cs = 0.f;
#pragma unroll
    for (int fm=0; fm<4; ++fm)
#pragma unroll
      for (int r=0; r<4; ++r) cs += __expf(acc[fm][fn][r]-cm);
    cs += __shfl_xor(cs, 16);
    cs += __shfl_xor(cs, 32);
    if (q == 0){
      const int n = n0 + wn + fn*16 + lm;
      CP[((size_t)z*NSEQ + n)*16 + yg] = cm;
      CS[((size_t)z*NSEQ + n)*16 + yg] = cs;
    }
  }
}

// -------- fold 16 partials per row/col -> rmax/rrcp, cmax/crcp --------------
// grid 256x256: gid<32768 rows, else cols. item = z*1024 + index.
__global__ __launch_bounds__(256)
void redstats_kernel(const float* __restrict__ RP, const float* __restrict__ RS,
                     const float* __restrict__ CP, const float* __restrict__ CS,
                     float* __restrict__ rmax, float* __restrict__ rrcp,
                     float* __restrict__ cmax, float* __restrict__ crcp)
{
  const int gid = blockIdx.x*256 + threadIdx.x;
  const bool isrow = gid < 32768;
  const int item = isrow ? gid : gid - 32768;
  const float* P = isrow ? RP : CP;
  const float* S = isrow ? RS : CS;
  float M = -1e30f;
#pragma unroll
  for (int g=0; g<16; g++) M = fmaxf(M, P[(size_t)item*16 + g]);
  float s = 0.f;
#pragma unroll
  for (int g=0; g<16; g++) s += S[(size_t)item*16 + g] * __expf(P[(size_t)item*16 + g] - M);
  if (isrow){ rmax[item] = M; rrcp[item] = 1.0f/s; }
  else      { cmax[item] = M; crcp[item] = 1.0f/s; }
}

// ------- split-K final projection: out_pre[4096,1024] @ WoT -> partials -----
__global__ __launch_bounds__(256)
void gemm8_kernel(const u16* __restrict__ A, const u16* __restrict__ B,
                  float* __restrict__ P)
{
  __shared__ __attribute__((aligned(16))) u16 sA[2][4096];
  __shared__ __attribute__((aligned(16))) u16 sB[2][4096];
  const int t = threadIdx.x;
  const int bid = blockIdx.x;
  const int w = (bid & 7)*128 + (bid >> 3);
  const int x = w & 7;          // N tile (0..7)
  const int y = (w >> 3) & 31;  // M tile (0..31)
  const int s = w >> 8;         // K slice (0..3)
  const int m0 = y*128, n0 = x*128, k0 = s*256;

  const int wave = t>>6, lane = t&63;
  const int wm = (wave>>1)*64, wn = (wave&1)*64;
  const int lm = lane&15, q = lane>>4;

  const f32x4 zero4 = {0.f,0.f,0.f,0.f};
  f32x4 acc[4][4];
#pragma unroll
  for (int i=0;i<4;i++)
#pragma unroll
    for (int j=0;j<4;j++) acc[i][j] = zero4;

  const int arowblk = wave*32;

  auto issueA = [&](int kt, int buf){
    const int kg = k0 + (kt<<5);
#pragma unroll
    for (int rr=0; rr<2; ++rr){
      const int rb = arowblk + rr*16;
      gload_lds16(A + (size_t)(m0+rb+lm)*1024 + (kg + q*8), &sA[buf][rb*32]);
    }
  };
  auto issueB = [&](int kt, int buf){
    const int kg = k0 + (kt<<5);
#pragma unroll
    for (int rr=0; rr<2; ++rr){
      const int rb = arowblk + rr*16;
      gload_lds16(B + (size_t)(n0+rb+lm)*1024 + (kg + q*8), &sB[buf][rb*32]);
    }
  };

  issueA(0, 0); issueB(0, 0);

  int cur = 0;
  for (int kt=0; kt<8; ++kt){
    __syncthreads();
    if (kt+1 < 8){
      issueA(kt+1, cur^1);
      issueB(kt+1, cur^1);
    }
    bf16x8 af[4], bfr[4];
#pragma unroll
    for (int f=0; f<4; ++f){
      af[f]  = *(const bf16x8*)&sA[cur][((wm>>4)+f)*512 + lane*8];
      bfr[f] = *(const bf16x8*)&sB[cur][((wn>>4)+f)*512 + lane*8];
    }
#pragma unroll
    for (int fm=0; fm<4; ++fm)
#pragma unroll
      for (int fn=0; fn<4; ++fn)
        acc[fm][fn] = __builtin_amdgcn_mfma_f32_16x16x32_bf16(af[fm], bfr[fn], acc[fm][fn], 0, 0, 0);
    cur ^= 1;
  }

  float* Pp = P + (size_t)s*4194304;   // 4096*1024 per slice
#pragma unroll
  for (int fm=0; fm<4; ++fm){
#pragma unroll
    for (int fn=0; fn<4; ++fn){
#pragma unroll
      for (int r=0; r<4; ++r){
        const int m = m0 + wm + fm*16 + q*4 + r;
        const int n = n0 + wn + fn*16 + lm;
        Pp[(size_t)m*1024 + n] = acc[fm][fn][r];
      }
    }
  }
}

// ------- reduce 4 fp32 partial planes + bias -> out (fp32) ------------------
__global__ __launch_bounds__(256)
void red8_kernel(const float* __restrict__ P, const float* __restrict__ bias,
                 float* __restrict__ out)
{
  const int idx = blockIdx.x*256 + threadIdx.x;   // float4 index, 1M total
  const float4* P4 = (const float4*)P;
  float4 a = P4[idx];
  float4 b = P4[idx + 1048576];
  float4 c = P4[idx + 2097152];
  float4 d = P4[idx + 3145728];
  float4 bb = ((const float4*)bias)[idx & 255];
  float4 o;
  o.x = a.x + b.x + c.x + d.x + bb.x;
  o.y = a.y + b.y + c.y + d.y + bb.y;
  o.z = a.z + b.z + c.z + d.z + bb.z;
  o.w = a.w + b.w + c.w + d.w + bb.w;
  ((float4*)out)[idx] = o;
}

// ------- transpose both operands: [32][1024][128] -> [32][128][1024] --------
__global__ __launch_bounds__(256)
void transpose2_kernel(const u16* __restrict__ cond, const u16* __restrict__ refv,
                       u16* __restrict__ condT, u16* __restrict__ refvT)
{
  __shared__ u16 tile[32][33];
  const int zz = blockIdx.z;
  const u16* X = (zz < 32) ? cond : refv;
  u16* XT      = (zz < 32) ? condT : refvT;
  const int z = zz & 31;
  const int i0 = blockIdx.y*32, d0 = blockIdx.x*32;
  const int t = threadIdx.x;
  const int tc = t & 31, tr = t >> 5;
  const u16* Xp = X + (size_t)z*NSEQ*DHEAD;
#pragma unroll
  for (int p=0;p<4;p++){
    int i = tr + p*8;
    tile[i][tc] = Xp[(size_t)(i0+i)*DHEAD + d0 + tc];
  }
  __syncthreads();
  u16* Op = XT + (size_t)z*DHEAD*NSEQ;
#pragma unroll
  for (int p=0;p<4;p++){
    int d = tr + p*8;
    Op[(size_t)(d0+d)*NSEQ + i0 + tc] = tile[tc][d];
  }
}

// ---------------- softmax + talking-heads mix ----------------
__global__ __launch_bounds__(256)
void mix_kernel(u16* simam,
                const float* __restrict__ rmax, const float* __restrict__ rrcp,
                const float* __restrict__ cmax, const float* __restrict__ crcp,
                const float* __restrict__ thw, const float* __restrict__ cthw,
                u16* __restrict__ cmT)
{
  __shared__ float s_th[64], s_cth[64];
  __shared__ u16 s_cm[8][32][33];
  const int t = threadIdx.x;
  if (t < 64){ s_th[t] = thw[t]; s_cth[t] = cthw[t]; }
  __syncthreads();
  const int b = blockIdx.z, i0 = blockIdx.y*32, j0 = blockIdx.x*32;
  const int tj = t & 31, ti = t >> 5;
  for (int p=0;p<4;p++){
    const int i = ti + p*8;
    float a[8], c[8];
#pragma unroll
    for (int h=0;h<8;h++){
      const int bh = b*8 + h;
      const float v = bf2f(simam[((size_t)bh*NSEQ + (i0+i))*NSEQ + j0 + tj]);
      a[h] = __expf(v - rmax[(size_t)bh*NSEQ + i0+i]) * rrcp[(size_t)bh*NSEQ + i0+i];
      c[h] = __expf(v - cmax[(size_t)bh*NSEQ + j0+tj]) * crcp[(size_t)bh*NSEQ + j0+tj];
    }
#pragma unroll
    for (int g=0;g<8;g++){
      float sa = 0.f, sc = 0.f;
#pragma unroll
      for (int h=0;h<8;h++){ sa += s_th[g*8+h]*a[h]; sc += s_cth[g*8+h]*c[h]; }
      simam[((size_t)(b*8+g)*NSEQ + (i0+i))*NSEQ + j0 + tj] = f2bf(sa);
      s_cm[g][i][tj] = f2bf(sc);
    }
  }
  __syncthreads();
#pragma unroll
  for (int g=0;g<8;g++){
#pragma unroll
    for (int p=0;p<4;p++){
      const int j = ti + p*8;
      cmT[((size_t)(b*8+g)*NSEQ + (j0+j))*NSEQ + i0 + tj] = s_cm[g][tj][j];
    }
  }
}

extern "C" void kernel_launch(void* const* d_in, const int* in_sizes, int n_in,
                              void* d_out, int out_size, void* d_ws, size_t ws_size,
                              hipStream_t stream)
{
  const float* x     = (const float*)d_in[0];
  const float* cinfo = (const float*)d_in[1];
  const float* ref   = (const float*)d_in[2];
  const float* ln_w  = (const float*)d_in[3];
  const float* ln_b  = (const float*)d_in[4];
  const float* cln_w = (const float*)d_in[5];
  const float* cln_b = (const float*)d_in[6];
  const float* Wk    = (const float*)d_in[7];
  const float* Wv    = (const float*)d_in[8];
  const float* Wo    = (const float*)d_in[9];
  const float* bo    = (const float*)d_in[10];
  const float* thw   = (const float*)d_in[11];
  const float* cthw  = (const float*)d_in[12];
  float* out = (float*)d_out;

  char* ws = (char*)d_ws;
  u16* xn    = (u16*)(ws + 0);          // 8 MB; reused as out_pre
  u16* cn    = (u16*)(ws + 8388608);    // 8 MB; reused for stats PARTIALS
  u16* rn    = (u16*)(ws + 16777216);   // 8 MB; reused for final stats
  u16* cond  = (u16*)(ws + 25165824);   // 8 MB  [b,h,i,d]
  u16* refv  = (u16*)(ws + 33554432);   // 8 MB  [b,h,j,d]
  u16* condT = (u16*)(ws + 41943040);   // 8 MB  [b,h,d,j]
  u16* refvT = (u16*)(ws + 50331648);   // 8 MB  [b,h,d,j]
  u16* sim   = (u16*)(ws + 58720256);   // 64 MB [b,h,i,j]; then step-8 partials
  u16* cmT   = (u16*)(ws + 125829120);  // 64 MB [b,g,j,i]
  u16* WkT   = (u16*)(ws + 192937984);  // 6 MB  [1024,3072] bf16
  u16* WvT   = (u16*)(ws + 199229440);  // 4 MB  [1024,2048] bf16
  u16* WoT   = (u16*)(ws + 203423744);  // 2 MB  [1024,1024] bf16
  // stats partials (in cn region, free after step 2): 4 x 2 MB fp32
  float* RP = (float*)(ws + 8388608);
  float* RS = (float*)(ws + 8388608 + 2097152);
  float* CP = (float*)(ws + 8388608 + 4194304);
  float* CS = (float*)(ws + 8388608 + 6291456);
  // final stats (in rn region, free after step 2): 4 x 128 KB fp32
  float* rmax = (float*)(ws + 16777216);
  float* rrcp = (float*)(ws + 16777216 + 131072);
  float* cmax = (float*)(ws + 16777216 + 262144);
  float* crcp = (float*)(ws + 16777216 + 393216);
  u16* out_pre = (u16*)(ws + 0);

  // 1) LayerNorms (fp32 -> bf16), all three in one launch
  ln3_kernel<<<dim3(4096,3), 256, 0, stream>>>(x, ref, cinfo, ln_w, ln_b,
                                               cln_w, cln_b, xn, rn, cn);

  // 1b) weight convert+transpose fp32[K,N] -> bf16[N,K]
  wcvt_kernel<<<dim3(96,32,3), 256, 0, stream>>>(Wk, Wv, Wo, WkT, WvT, WoT);

  // 2) fused projections (BK=64; r5 best config):
  //    z=0 -> [xn|cn|rn]@Wk -> cond; z=1 -> [xn|rn]@Wv -> refv
  gemm_kernel<64><<<dim3(8,32,2), 256, 0, stream>>>(
      xn, cn, rn, xn, rn, WkT, WvT, cond, refv, nullptr,
      3072, 2048, DIM, 3072, 2048, 0, 0, 0, 0, 3, 3, 1, 1.0f);

  // 3) transposed copies for the PV/context GEMM B-operands (one launch)
  transpose2_kernel<<<dim3(4,32,64), 256, 0, stream>>>(cond, refv, condT, refvT);

  // 4+5) sim = cond @ refv^T * scale WITH fused softmax partial stats,
  //      then tiny partial-fold kernel -> rmax/rrcp/cmax/crcp
  gemmqk_kernel<<<dim3(8,8,32), 256, 0, stream>>>(cond, refv, sim, RP, RS, CP, CS);
  redstats_kernel<<<256, 256, 0, stream>>>(RP, RS, CP, CS, rmax, rrcp, cmax, crcp);

  // 6) both softmaxes + talking heads (am in-place over sim; cmT transposed)
  mix_kernel<<<dim3(32,32,4), 256, 0, stream>>>(sim, rmax, rrcp, cmax, crcp, thw, cthw, cmT);

  // 7) fused (BK=64): z<32: am@refvT -> out_pre (bf16 head-merge);
  //    z>=32: cmT@condT -> ctx out (fp32)
  gemm_kernel<64><<<dim3(1,8,64), 256, 0, stream>>>(
      sim, sim, sim, cmT, cmT, refvT, condT, out_pre, out + (size_t)BATCH*NSEQ*DIM, nullptr,
      1024, 1024, NSEQ, NSEQ, NSEQ, 0,
      (long)NSEQ*NSEQ, (long)DHEAD*NSEQ, 0, 1, 4, 32, 1.0f);

  // 8) final projection, split-K=4 + chunked XCD swizzle: partials into sim
  //    region (dead after step 7), then deterministic reduce + bias.
  gemm8_kernel<<<1024, 256, 0, stream>>>(out_pre, WoT, (float*)sim);
  red8_kernel<<<4096, 256, 0, stream>>>((const float*)sim, bo, out);
}

// Round 10
// 446.834 us; speedup vs baseline: 1.3295x; 1.0012x over previous
//
#include <hip/hip_runtime.h>
#include <hip/hip_bf16.h>
#include <stdint.h>

typedef unsigned short u16;
typedef __attribute__((ext_vector_type(8))) short bf16x8;
typedef __attribute__((ext_vector_type(4))) float f32x4;

#define HEADS 8
#define DHEAD 128
#define NSEQ 1024
#define BATCH 4
#define DIM 1024
#define ATT_SCALE 0.088388347648318447f  // 1/sqrt(128)

static __device__ __forceinline__ float bf2f(u16 u){
  union { unsigned int i; float f; } c; c.i = ((unsigned int)u) << 16; return c.f;
}
static __device__ __forceinline__ u16 f2bf(float f){
  union { float f; unsigned int i; } c; c.f = f;
  unsigned int x = c.i;
  return (u16)((x + 0x7fffu + ((x >> 16) & 1u)) >> 16);
}

// async global->LDS, 16B per lane, dest = wave-uniform base + lane*16
static __device__ __forceinline__ void gload_lds16(const void* g, void* l){
  __builtin_amdgcn_global_load_lds((__attribute__((address_space(1))) void*)(g),
                                   (__attribute__((address_space(3))) void*)(l),
                                   16, 0, 0);
}

// ---------------- LayerNorm x3 fused: fp32 in, bf16 out ---------------------
// grid (4096, 3): y=0 x->xn (ln), y=1 ref->rn (ln), y=2 cinfo->cn (cln)
__global__ __launch_bounds__(256)
void ln3_kernel(const float* __restrict__ x, const float* __restrict__ ref,
                const float* __restrict__ cinfo,
                const float* __restrict__ ln_w, const float* __restrict__ ln_b,
                const float* __restrict__ cln_w, const float* __restrict__ cln_b,
                u16* __restrict__ xn, u16* __restrict__ rn, u16* __restrict__ cn)
{
  const int z = blockIdx.y;
  const float* src = (z==0) ? x : (z==1) ? ref : cinfo;
  const float* w   = (z==2) ? cln_w : ln_w;
  const float* b   = (z==2) ? cln_b : ln_b;
  u16* out         = (z==0) ? xn : (z==1) ? rn : cn;

  const int row = blockIdx.x;
  const int t = threadIdx.x;
  const float* xr = src + (size_t)row * DIM;
  float4 v4 = *(const float4*)(xr + t*4);
  float v[4] = {v4.x, v4.y, v4.z, v4.w};
  float s = v[0]+v[1]+v[2]+v[3];
  __shared__ float red[256];
  red[t] = s; __syncthreads();
  for (int o=128;o;o>>=1){ if (t<o) red[t]+=red[t+o]; __syncthreads(); }
  const float mean = red[0] * (1.0f/DIM);
  __syncthreads();
  s = 0.f;
#pragma unroll
  for (int i=0;i<4;i++){ float d = v[i]-mean; s += d*d; }
  red[t] = s; __syncthreads();
  for (int o=128;o;o>>=1){ if (t<o) red[t]+=red[t+o]; __syncthreads(); }
  const float rstd = rsqrtf(red[0]*(1.0f/DIM) + 1e-5f);
  float4 w4 = *(const float4*)(w + t*4);
  float4 b4 = *(const float4*)(b + t*4);
  float wv[4] = {w4.x, w4.y, w4.z, w4.w};
  float bv[4] = {b4.x, b4.y, b4.z, b4.w};
  union { uint2 u; u16 s[4]; } ov;
#pragma unroll
  for (int i=0;i<4;i++)
    ov.s[i] = f2bf((v[i]-mean)*rstd*wv[i] + bv[i]);
  *(uint2*)(out + (size_t)row*DIM + t*4) = ov.u;
}

// -------- weight convert+transpose: fp32 [K,1024] -> bf16 [1024,K] ----------
__global__ __launch_bounds__(256)
void wcvt_kernel(const float* __restrict__ Wk, const float* __restrict__ Wv,
                 const float* __restrict__ Wo,
                 u16* __restrict__ WkT, u16* __restrict__ WvT, u16* __restrict__ WoT)
{
  const int z = blockIdx.z;
  const int K = (z==0) ? 3072 : (z==1) ? 2048 : 1024;
  if ((int)blockIdx.x*32 >= K) return;
  const float* W = (z==0) ? Wk : (z==1) ? Wv : Wo;
  u16* WT = (z==0) ? WkT : (z==1) ? WvT : WoT;
  __shared__ float tile[32][33];
  const int k0 = blockIdx.x*32, n0 = blockIdx.y*32;
  const int t = threadIdx.x, tc = t&31, tr = t>>5;
#pragma unroll
  for (int p=0;p<4;p++)
    tile[tr+p*8][tc] = W[(size_t)(k0+tr+p*8)*DIM + n0+tc];
  __syncthreads();
#pragma unroll
  for (int p=0;p<4;p++)
    WT[(size_t)(n0+tr+p*8)*K + k0+tc] = f2bf(tile[tc][tr+p*8]);
}

// ------- MFMA GEMM, 4-phase pipelined (T3+T4+T5 port), BK=64 ---------------
// Same math/LDS layout as the verified 2-barrier kernel (conflict-free,
// bitwise-identical accumulation order). Schedule per K-tile (BK=64, 2 subs):
//   P0: ds_read sub0 af0-1+bf0-3 | issue A-sub0(t+1) | bar | prio1 8MFMA prio0 | bar
//   P1: ds_read sub0 af2-3       | issue B-sub0(t+1) | vmcnt(4) bar | 8MFMA | bar
//   P2: ds_read sub1 af0-1+bf0-3 | issue A-sub1(t+1) | bar | 8MFMA | bar
//   P3: ds_read sub1 af2-3       | issue B-sub1(t+1) | vmcnt(4) bar | 8MFMA | bar
// vmcnt(4) at P1 drains tile-t's sub1 loads (oldest 4 of <=8 outstanding);
// at P3 drains t+1's sub0. Never 0 mid-loop; loads span ~3 phase boundaries.
// Buffer safety: t+1 writes buf^1 whose last reader (t-1) finished before the
// t-1 P3 trailing barrier. Tail tiles use vmcnt(0).
// epi: 0 bf16 plane*alpha | 1 bf16 head-merge | 2 fp32 +bias | 3 bf16
//      head-split | 4 fp32 head-merge
__global__ __launch_bounds__(256)
void gemm_kernel(const u16* __restrict__ A0, const u16* __restrict__ A1,
                 const u16* __restrict__ A2, const u16* __restrict__ A0b,
                 const u16* __restrict__ A1b,
                 const u16* __restrict__ B1, const u16* __restrict__ B2,
                 void* __restrict__ Cv, void* __restrict__ Cv2,
                 const float* __restrict__ bias,
                 int K1, int K2, int lda, int ldb1, int ldb2, int ldc,
                 long a_plane, long b_plane, long c_plane,
                 int epi1, int epi2, int z_split, float alpha)
{
  __shared__ __attribute__((aligned(16))) u16 sA[2][8192];
  __shared__ __attribute__((aligned(16))) u16 sB[2][8192];
  const int t = threadIdx.x;
  const int m0 = blockIdx.y*128, n0 = blockIdx.x*128;
  const int zz = blockIdx.z;
  const bool side = (zz >= z_split);
  const int z = side ? (zz - z_split) : zz;
  const u16* a0 = (side ? A0b : A0) + (size_t)z*a_plane;
  const u16* a1 = (side ? A1b : A1) + (size_t)z*a_plane;
  const u16* a2 = A2 + (size_t)z*a_plane;
  const u16* bB = (side ? B2 : B1) + (size_t)z*b_plane;
  void* Cp = side ? Cv2 : Cv;
  const int EPI = side ? epi2 : epi1;
  const int K   = side ? K2 : K1;
  const int ldb = side ? ldb2 : ldb1;

  const int wave = t>>6, lane = t&63;
  const int wm = (wave>>1)*64, wn = (wave&1)*64;
  const int lm = lane&15, q = lane>>4;

  const f32x4 zero4 = {0.f,0.f,0.f,0.f};
  f32x4 acc[4][4];
#pragma unroll
  for (int i=0;i<4;i++)
#pragma unroll
    for (int j=0;j<4;j++) acc[i][j] = zero4;

  const int arowblk = wave*32;
  const int KT = K >> 6;                    // BK = 64

  // 2 gloads each: one 16-row-block pair for (tile kt, sub)
  auto issueA2 = [&](int kt, int buf, int sub){
    const int kg = kt<<6, seg = kg>>10, ka = kg&1023;
    const u16* Ap = (seg==0) ? a0 : (seg==1 ? a1 : a2);
#pragma unroll
    for (int rr=0; rr<2; ++rr){
      const int rb = arowblk + rr*16;
      gload_lds16(Ap + (size_t)(m0+rb+lm)*lda + (ka + sub*32 + q*8),
                  &sA[buf][sub*4096 + rb*32]);
    }
  };
  auto issueB2 = [&](int kt, int buf, int sub){
    const int kg = kt<<6;
#pragma unroll
    for (int rr=0; rr<2; ++rr){
      const int rb = arowblk + rr*16;
      gload_lds16(bB + (size_t)(n0+rb+lm)*ldb + (kg + sub*32 + q*8),
                  &sB[buf][sub*4096 + rb*32]);
    }
  };

  // prologue: fully stage tile 0 into buf 0, drain, sync
  issueA2(0,0,0); issueB2(0,0,0); issueA2(0,0,1); issueB2(0,0,1);
  asm volatile("s_waitcnt vmcnt(0)" ::: "memory");
  __builtin_amdgcn_s_barrier();

  int cur = 0;
  for (int kt=0; kt<KT; ++kt){
    const bool pf = (kt+1 < KT);
    bf16x8 afA, afB, bf0, bf1, bf2, bf3;

    // ---------------- P0: sub0 -------------------------------------------
    afA = *(const bf16x8*)&sA[cur][((wm>>4)+0)*512 + lane*8];
    afB = *(const bf16x8*)&sA[cur][((wm>>4)+1)*512 + lane*8];
    bf0 = *(const bf16x8*)&sB[cur][((wn>>4)+0)*512 + lane*8];
    bf1 = *(const bf16x8*)&sB[cur][((wn>>4)+1)*512 + lane*8];
    bf2 = *(const bf16x8*)&sB[cur][((wn>>4)+2)*512 + lane*8];
    bf3 = *(const bf16x8*)&sB[cur][((wn>>4)+3)*512 + lane*8];
    if (pf) issueA2(kt+1, cur^1, 0);
    __builtin_amdgcn_s_barrier();
    __builtin_amdgcn_s_setprio(1);
    acc[0][0] = __builtin_amdgcn_mfma_f32_16x16x32_bf16(afA, bf0, acc[0][0], 0,0,0);
    acc[0][1] = __builtin_amdgcn_mfma_f32_16x16x32_bf16(afA, bf1, acc[0][1], 0,0,0);
    acc[0][2] = __builtin_amdgcn_mfma_f32_16x16x32_bf16(afA, bf2, acc[0][2], 0,0,0);
    acc[0][3] = __builtin_amdgcn_mfma_f32_16x16x32_bf16(afA, bf3, acc[0][3], 0,0,0);
    acc[1][0] = __builtin_amdgcn_mfma_f32_16x16x32_bf16(afB, bf0, acc[1][0], 0,0,0);
    acc[1][1] = __builtin_amdgcn_mfma_f32_16x16x32_bf16(afB, bf1, acc[1][1], 0,0,0);
    acc[1][2] = __builtin_amdgcn_mfma_f32_16x16x32_bf16(afB, bf2, acc[1][2], 0,0,0);
    acc[1][3] = __builtin_amdgcn_mfma_f32_16x16x32_bf16(afB, bf3, acc[1][3], 0,0,0);
    __builtin_amdgcn_s_setprio(0);
    __builtin_amdgcn_s_barrier();

    // ---------------- P1: sub0 tail --------------------------------------
    afA = *(const bf16x8*)&sA[cur][((wm>>4)+2)*512 + lane*8];
    afB = *(const bf16x8*)&sA[cur][((wm>>4)+3)*512 + lane*8];
    if (pf){
      issueB2(kt+1, cur^1, 0);
      asm volatile("s_waitcnt vmcnt(4)" ::: "memory");   // tile-t sub1 done
    } else {
      asm volatile("s_waitcnt vmcnt(0)" ::: "memory");
    }
    __builtin_amdgcn_s_barrier();
    __builtin_amdgcn_s_setprio(1);
    acc[2][0] = __builtin_amdgcn_mfma_f32_16x16x32_bf16(afA, bf0, acc[2][0], 0,0,0);
    acc[2][1] = __builtin_amdgcn_mfma_f32_16x16x32_bf16(afA, bf1, acc[2][1], 0,0,0);
    acc[2][2] = __builtin_amdgcn_mfma_f32_16x16x32_bf16(afA, bf2, acc[2][2], 0,0,0);
    acc[2][3] = __builtin_amdgcn_mfma_f32_16x16x32_bf16(afA, bf3, acc[2][3], 0,0,0);
    acc[3][0] = __builtin_amdgcn_mfma_f32_16x16x32_bf16(afB, bf0, acc[3][0], 0,0,0);
    acc[3][1] = __builtin_amdgcn_mfma_f32_16x16x32_bf16(afB, bf1, acc[3][1], 0,0,0);
    acc[3][2] = __builtin_amdgcn_mfma_f32_16x16x32_bf16(afB, bf2, acc[3][2], 0,0,0);
    acc[3][3] = __builtin_amdgcn_mfma_f32_16x16x32_bf16(afB, bf3, acc[3][3], 0,0,0);
    __builtin_amdgcn_s_setprio(0);
    __builtin_amdgcn_s_barrier();

    // ---------------- P2: sub1 -------------------------------------------
    afA = *(const bf16x8*)&sA[cur][4096 + ((wm>>4)+0)*512 + lane*8];
    afB = *(const bf16x8*)&sA[cur][4096 + ((wm>>4)+1)*512 + lane*8];
    bf0 = *(const bf16x8*)&sB[cur][4096 + ((wn>>4)+0)*512 + lane*8];
    bf1 = *(const bf16x8*)&sB[cur][4096 + ((wn>>4)+1)*512 + lane*8];
    bf2 = *(const bf16x8*)&sB[cur][4096 + ((wn>>4)+2)*512 + lane*8];
    bf3 = *(const bf16x8*)&sB[cur][4096 + ((wn>>4)+3)*512 + lane*8];
    if (pf) issueA2(kt+1, cur^1, 1);
    __builtin_amdgcn_s_barrier();
    __builtin_amdgcn_s_setprio(1);
    acc[0][0] = __builtin_amdgcn_mfma_f32_16x16x32_bf16(afA, bf0, acc[0][0], 0,0,0);
    acc[0][1] = __builtin_amdgcn_mfma_f32_16x16x32_bf16(afA, bf1, acc[0][1], 0,0,0);
    acc[0][2] = __builtin_amdgcn_mfma_f32_16x16x32_bf16(afA, bf2, acc[0][2], 0,0,0);
    acc[0][3] = __builtin_amdgcn_mfma_f32_16x16x32_bf16(afA, bf3, acc[0][3], 0,0,0);
    acc[1][0] = __builtin_amdgcn_mfma_f32_16x16x32_bf16(afB, bf0, acc[1][0], 0,0,0);
    acc[1][1] = __builtin_amdgcn_mfma_f32_16x16x32_bf16(afB, bf1, acc[1][1], 0,0,0);
    acc[1][2] = __builtin_amdgcn_mfma_f32_16x16x32_bf16(afB, bf2, acc[1][2], 0,0,0);
    acc[1][3] = __builtin_amdgcn_mfma_f32_16x16x32_bf16(afB, bf3, acc[1][3], 0,0,0);
    __builtin_amdgcn_s_setprio(0);
    __builtin_amdgcn_s_barrier();

    // ---------------- P3: sub1 tail --------------------------------------
    afA = *(const bf16x8*)&sA[cur][4096 + ((wm>>4)+2)*512 + lane*8];
    afB = *(const bf16x8*)&sA[cur][4096 + ((wm>>4)+3)*512 + lane*8];
    if (pf){
      issueB2(kt+1, cur^1, 1);
      asm volatile("s_waitcnt vmcnt(4)" ::: "memory");   // tile-(t+1) sub0 done
    }
    __builtin_amdgcn_s_barrier();
    __builtin_amdgcn_s_setprio(1);
    acc[2][0] = __builtin_amdgcn_mfma_f32_16x16x32_bf16(afA, bf0, acc[2][0], 0,0,0);
    acc[2][1] = __builtin_amdgcn_mfma_f32_16x16x32_bf16(afA, bf1, acc[2][1], 0,0,0);
    acc[2][2] = __builtin_amdgcn_mfma_f32_16x16x32_bf16(afA, bf2, acc[2][2], 0,0,0);
    acc[2][3] = __builtin_amdgcn_mfma_f32_16x16x32_bf16(afA, bf3, acc[2][3], 0,0,0);
    acc[3][0] = __builtin_amdgcn_mfma_f32_16x16x32_bf16(afB, bf0, acc[3][0], 0,0,0);
    acc[3][1] = __builtin_amdgcn_mfma_f32_16x16x32_bf16(afB, bf1, acc[3][1], 0,0,0);
    acc[3][2] = __builtin_amdgcn_mfma_f32_16x16x32_bf16(afB, bf2, acc[3][2], 0,0,0);
    acc[3][3] = __builtin_amdgcn_mfma_f32_16x16x32_bf16(afB, bf3, acc[3][3], 0,0,0);
    __builtin_amdgcn_s_setprio(0);
    __builtin_amdgcn_s_barrier();

    cur ^= 1;
  }

#pragma unroll
  for (int fm=0; fm<4; ++fm){
#pragma unroll
    for (int fn=0; fn<4; ++fn){
#pragma unroll
      for (int r=0; r<4; ++r){
        const int m = m0 + wm + fm*16 + q*4 + r;
        const int n = n0 + wn + fn*16 + lm;
        float val = acc[fm][fn][r] * alpha;
        if (EPI == 0){
          ((u16*)Cp)[(size_t)z*c_plane + (size_t)m*ldc + n] = f2bf(val);
        } else if (EPI == 1){
          ((u16*)Cp)[((size_t)(z>>3)*NSEQ + m)*DIM + (size_t)(z&7)*DHEAD + n] = f2bf(val);
        } else if (EPI == 2){
          ((float*)Cp)[(size_t)m*ldc + n] = val + bias[n];
        } else if (EPI == 3){
          ((u16*)Cp)[(size_t)(((m>>10)*HEADS + (n>>7))*NSEQ + (m&1023))*DHEAD + (n&127)] = f2bf(val);
        } else {
          ((float*)Cp)[((size_t)(z>>3)*NSEQ + m)*DIM + (size_t)(z&7)*DHEAD + n] = val;
        }
      }
    }
  }
}

// -------- sim GEMM + fused softmax partial stats (steps 4+5) ---------------
__global__ __launch_bounds__(256)
void gemmqk_kernel(const u16* __restrict__ cond, const u16* __restrict__ refv,
                   u16* __restrict__ sim,
                   float* __restrict__ RP, float* __restrict__ RS,
                   float* __restrict__ CP, float* __restrict__ CS)
{
  __shared__ __attribute__((aligned(16))) u16 sA[2][4096];
  __shared__ __attribute__((aligned(16))) u16 sB[2][4096];
  const int t = threadIdx.x;
  const int m0 = blockIdx.y*128, n0 = blockIdx.x*128;
  const int z = blockIdx.z;
  const u16* A = cond + (size_t)z*NSEQ*DHEAD;
  const u16* B = refv + (size_t)z*NSEQ*DHEAD;

  const int wave = t>>6, lane = t&63;
  const int wm = (wave>>1)*64, wn = (wave&1)*64;
  const int lm = lane&15, q = lane>>4;

  const f32x4 zero4 = {0.f,0.f,0.f,0.f};
  f32x4 acc[4][4];
#pragma unroll
  for (int i=0;i<4;i++)
#pragma unroll
    for (int j=0;j<4;j++) acc[i][j] = zero4;

  const int arowblk = wave*32;

  auto issueA = [&](int kt, int buf){
    const int kg = kt<<5;
#pragma unroll
    for (int rr=0; rr<2; ++rr){
      const int rb = arowblk + rr*16;
      gload_lds16(A + (size_t)(m0+rb+lm)*DHEAD + (kg + q*8), &sA[buf][rb*32]);
    }
  };
  auto issueB = [&](int kt, int buf){
    const int kg = kt<<5;
#pragma unroll
    for (int rr=0; rr<2; ++rr){
      const int rb = arowblk + rr*16;
      gload_lds16(B + (size_t)(n0+rb+lm)*DHEAD + (kg + q*8), &sB[buf][rb*32]);
    }
  };

  issueA(0, 0); issueB(0, 0);

  int cur = 0;
  for (int kt=0; kt<4; ++kt){                 // K=128, BK=32
    __syncthreads();
    if (kt+1 < 4){
      issueA(kt+1, cur^1);
      issueB(kt+1, cur^1);
    }
    bf16x8 af[4], bfr[4];
#pragma unroll
    for (int f=0; f<4; ++f){
      af[f]  = *(const bf16x8*)&sA[cur][((wm>>4)+f)*512 + lane*8];
      bfr[f] = *(const bf16x8*)&sB[cur][((wn>>4)+f)*512 + lane*8];
    }
#pragma unroll
    for (int fm=0; fm<4; ++fm)
#pragma unroll
      for (int fn=0; fn<4; ++fn)
        acc[fm][fn] = __builtin_amdgcn_mfma_f32_16x16x32_bf16(af[fm], bfr[fn], acc[fm][fn], 0, 0, 0);
    cur ^= 1;
  }

  // epilogue: store bf16 sim; keep bf16-rounded fp32 values in acc
#pragma unroll
  for (int fm=0; fm<4; ++fm){
#pragma unroll
    for (int fn=0; fn<4; ++fn){
#pragma unroll
      for (int r=0; r<4; ++r){
        const int m = m0 + wm + fm*16 + q*4 + r;
        const int n = n0 + wn + fn*16 + lm;
        const u16 bv = f2bf(acc[fm][fn][r] * ATT_SCALE);
        sim[((size_t)z*NSEQ + m)*NSEQ + n] = bv;
        acc[fm][fn][r] = bf2f(bv);
      }
    }
  }

  // row partials
  const int xg = blockIdx.x*2 + (wn>>6);
#pragma unroll
  for (int fm=0; fm<4; ++fm){
#pragma unroll
    for (int r=0; r<4; ++r){
      float rm = fmaxf(fmaxf(acc[fm][0][r], acc[fm][1][r]),
                       fmaxf(acc[fm][2][r], acc[fm][3][r]));
#pragma unroll
      for (int msk=1; msk<16; msk<<=1) rm = fmaxf(rm, __shfl_xor(rm, msk));
      float rs = __expf(acc[fm][0][r]-rm) + __expf(acc[fm][1][r]-rm)
               + __expf(acc[fm][2][r]-rm) + __expf(acc[fm][3][r]-rm);
#pragma unroll
      for (int msk=1; msk<16; msk<<=1) rs += __shfl_xor(rs, msk);
      if (lm == 0){
        const int m = m0 + wm + fm*16 + q*4 + r;
        RP[((size_t)z*NSEQ + m)*16 + xg] = rm;
        RS[((size_t)z*NSEQ + m)*16 + xg] = rs;
      }
    }
  }

  // col partials
  const int yg = blockIdx.y*2 + (wm>>6);
#pragma unroll
  for (int fn=0; fn<4; ++fn){
    float cm = -1e30f;
#pragma unroll
    for (int fm=0; fm<4; ++fm)
#pragma unroll
      for (int r=0; r<4; ++r) cm = fmaxf(cm, acc[fm][fn][r]);
    cm = fmaxf(cm, __shfl_xor(cm, 16));
    cm = fmaxf(cm, __shfl_xor(cm, 32));
    float cs = 0.f;
#pragma unroll
    for (int fm=0; fm<4; ++fm)
#pragma unroll
      for (int r=0; r<4; ++r) cs += __expf(acc[fm][fn][r]-cm);
    cs += __shfl_xor(cs, 16);
    cs += __shfl_xor(cs, 32);
    if (q == 0){
      const int n = n0 + wn + fn*16 + lm;
      CP[((size_t)z*NSEQ + n)*16 + yg] = cm;
      CS[((size_t)z*NSEQ + n)*16 + yg] = cs;
    }
  }
}

// -------- fold 16 partials per row/col -> rmax/rrcp, cmax/crcp --------------
__global__ __launch_bounds__(256)
void redstats_kernel(const float* __restrict__ RP, const float* __restrict__ RS,
                     const float* __restrict__ CP, const float* __restrict__ CS,
                     float* __restrict__ rmax, float* __restrict__ rrcp,
                     float* __restrict__ cmax, float* __restrict__ crcp)
{
  const int gid = blockIdx.x*256 + threadIdx.x;
  const bool isrow = gid < 32768;
  const int item = isrow ? gid : gid - 32768;
  const float* P = isrow ? RP : CP;
  const float* S = isrow ? RS : CS;
  float M = -1e30f;
#pragma unroll
  for (int g=0; g<16; g++) M = fmaxf(M, P[(size_t)item*16 + g]);
  float s = 0.f;
#pragma unroll
  for (int g=0; g<16; g++) s += S[(size_t)item*16 + g] * __expf(P[(size_t)item*16 + g] - M);
  if (isrow){ rmax[item] = M; rrcp[item] = 1.0f/s; }
  else      { cmax[item] = M; crcp[item] = 1.0f/s; }
}

// ------- split-K final projection: out_pre[4096,1024] @ WoT -> partials -----
__global__ __launch_bounds__(256)
void gemm8_kernel(const u16* __restrict__ A, const u16* __restrict__ B,
                  float* __restrict__ P)
{
  __shared__ __attribute__((aligned(16))) u16 sA[2][4096];
  __shared__ __attribute__((aligned(16))) u16 sB[2][4096];
  const int t = threadIdx.x;
  const int bid = blockIdx.x;
  const int w = (bid & 7)*128 + (bid >> 3);
  const int x = w & 7;          // N tile (0..7)
  const int y = (w >> 3) & 31;  // M tile (0..31)
  const int s = w >> 8;         // K slice (0..3)
  const int m0 = y*128, n0 = x*128, k0 = s*256;

  const int wave = t>>6, lane = t&63;
  const int wm = (wave>>1)*64, wn = (wave&1)*64;
  const int lm = lane&15, q = lane>>4;

  const f32x4 zero4 = {0.f,0.f,0.f,0.f};
  f32x4 acc[4][4];
#pragma unroll
  for (int i=0;i<4;i++)
#pragma unroll
    for (int j=0;j<4;j++) acc[i][j] = zero4;

  const int arowblk = wave*32;

  auto issueA = [&](int kt, int buf){
    const int kg = k0 + (kt<<5);
#pragma unroll
    for (int rr=0; rr<2; ++rr){
      const int rb = arowblk + rr*16;
      gload_lds16(A + (size_t)(m0+rb+lm)*1024 + (kg + q*8), &sA[buf][rb*32]);
    }
  };
  auto issueB = [&](int kt, int buf){
    const int kg = k0 + (kt<<5);
#pragma unroll
    for (int rr=0; rr<2; ++rr){
      const int rb = arowblk + rr*16;
      gload_lds16(B + (size_t)(n0+rb+lm)*1024 + (kg + q*8), &sB[buf][rb*32]);
    }
  };

  issueA(0, 0); issueB(0, 0);

  int cur = 0;
  for (int kt=0; kt<8; ++kt){
    __syncthreads();
    if (kt+1 < 8){
      issueA(kt+1, cur^1);
      issueB(kt+1, cur^1);
    }
    bf16x8 af[4], bfr[4];
#pragma unroll
    for (int f=0; f<4; ++f){
      af[f]  = *(const bf16x8*)&sA[cur][((wm>>4)+f)*512 + lane*8];
      bfr[f] = *(const bf16x8*)&sB[cur][((wn>>4)+f)*512 + lane*8];
    }
#pragma unroll
    for (int fm=0; fm<4; ++fm)
#pragma unroll
      for (int fn=0; fn<4; ++fn)
        acc[fm][fn] = __builtin_amdgcn_mfma_f32_16x16x32_bf16(af[fm], bfr[fn], acc[fm][fn], 0, 0, 0);
    cur ^= 1;
  }

  float* Pp = P + (size_t)s*4194304;   // 4096*1024 per slice
#pragma unroll
  for (int fm=0; fm<4; ++fm){
#pragma unroll
    for (int fn=0; fn<4; ++fn){
#pragma unroll
      for (int r=0; r<4; ++r){
        const int m = m0 + wm + fm*16 + q*4 + r;
        const int n = n0 + wn + fn*16 + lm;
        Pp[(size_t)m*1024 + n] = acc[fm][fn][r];
      }
    }
  }
}

// ------- reduce 4 fp32 partial planes + bias -> out (fp32) ------------------
__global__ __launch_bounds__(256)
void red8_kernel(const float* __restrict__ P, const float* __restrict__ bias,
                 float* __restrict__ out)
{
  const int idx = blockIdx.x*256 + threadIdx.x;   // float4 index, 1M total
  const float4* P4 = (const float4*)P;
  float4 a = P4[idx];
  float4 b = P4[idx + 1048576];
  float4 c = P4[idx + 2097152];
  float4 d = P4[idx + 3145728];
  float4 bb = ((const float4*)bias)[idx & 255];
  float4 o;
  o.x = a.x + b.x + c.x + d.x + bb.x;
  o.y = a.y + b.y + c.y + d.y + bb.y;
  o.z = a.z + b.z + c.z + d.z + bb.z;
  o.w = a.w + b.w + c.w + d.w + bb.w;
  ((float4*)out)[idx] = o;
}

// ------- transpose both operands: [32][1024][128] -> [32][128][1024] --------
__global__ __launch_bounds__(256)
void transpose2_kernel(const u16* __restrict__ cond, const u16* __restrict__ refv,
                       u16* __restrict__ condT, u16* __restrict__ refvT)
{
  __shared__ u16 tile[32][33];
  const int zz = blockIdx.z;
  const u16* X = (zz < 32) ? cond : refv;
  u16* XT      = (zz < 32) ? condT : refvT;
  const int z = zz & 31;
  const int i0 = blockIdx.y*32, d0 = blockIdx.x*32;
  const int t = threadIdx.x;
  const int tc = t & 31, tr = t >> 5;
  const u16* Xp = X + (size_t)z*NSEQ*DHEAD;
#pragma unroll
  for (int p=0;p<4;p++){
    int i = tr + p*8;
    tile[i][tc] = Xp[(size_t)(i0+i)*DHEAD + d0 + tc];
  }
  __syncthreads();
  u16* Op = XT + (size_t)z*DHEAD*NSEQ;
#pragma unroll
  for (int p=0;p<4;p++){
    int d = tr + p*8;
    Op[(size_t)(d0+d)*NSEQ + i0 + tc] = tile[tc][d];
  }
}

// ---------------- softmax + talking-heads mix ----------------
__global__ __launch_bounds__(256)
void mix_kernel(u16* simam,
                const float* __restrict__ rmax, const float* __restrict__ rrcp,
                const float* __restrict__ cmax, const float* __restrict__ crcp,
                const float* __restrict__ thw, const float* __restrict__ cthw,
                u16* __restrict__ cmT)
{
  __shared__ float s_th[64], s_cth[64];
  __shared__ u16 s_cm[8][32][33];
  const int t = threadIdx.x;
  if (t < 64){ s_th[t] = thw[t]; s_cth[t] = cthw[t]; }
  __syncthreads();
  const int b = blockIdx.z, i0 = blockIdx.y*32, j0 = blockIdx.x*32;
  const int tj = t & 31, ti = t >> 5;
  for (int p=0;p<4;p++){
    const int i = ti + p*8;
    float a[8], c[8];
#pragma unroll
    for (int h=0;h<8;h++){
      const int bh = b*8 + h;
      const float v = bf2f(simam[((size_t)bh*NSEQ + (i0+i))*NSEQ + j0 + tj]);
      a[h] = __expf(v - rmax[(size_t)bh*NSEQ + i0+i]) * rrcp[(size_t)bh*NSEQ + i0+i];
      c[h] = __expf(v - cmax[(size_t)bh*NSEQ + j0+tj]) * crcp[(size_t)bh*NSEQ + j0+tj];
    }
#pragma unroll
    for (int g=0;g<8;g++){
      float sa = 0.f, sc = 0.f;
#pragma unroll
      for (int h=0;h<8;h++){ sa += s_th[g*8+h]*a[h]; sc += s_cth[g*8+h]*c[h]; }
      simam[((size_t)(b*8+g)*NSEQ + (i0+i))*NSEQ + j0 + tj] = f2bf(sa);
      s_cm[g][i][tj] = f2bf(sc);
    }
  }
  __syncthreads();
#pragma unroll
  for (int g=0;g<8;g++){
#pragma unroll
    for (int p=0;p<4;p++){
      const int j = ti + p*8;
      cmT[((size_t)(b*8+g)*NSEQ + (j0+j))*NSEQ + i0 + tj] = s_cm[g][tj][j];
    }
  }
}

extern "C" void kernel_launch(void* const* d_in, const int* in_sizes, int n_in,
                              void* d_out, int out_size, void* d_ws, size_t ws_size,
                              hipStream_t stream)
{
  const float* x     = (const float*)d_in[0];
  const float* cinfo = (const float*)d_in[1];
  const float* ref   = (const float*)d_in[2];
  const float* ln_w  = (const float*)d_in[3];
  const float* ln_b  = (const float*)d_in[4];
  const float* cln_w = (const float*)d_in[5];
  const float* cln_b = (const float*)d_in[6];
  const float* Wk    = (const float*)d_in[7];
  const float* Wv    = (const float*)d_in[8];
  const float* Wo    = (const float*)d_in[9];
  const float* bo    = (const float*)d_in[10];
  const float* thw   = (const float*)d_in[11];
  const float* cthw  = (const float*)d_in[12];
  float* out = (float*)d_out;

  char* ws = (char*)d_ws;
  u16* xn    = (u16*)(ws + 0);          // 8 MB; reused as out_pre
  u16* cn    = (u16*)(ws + 8388608);    // 8 MB; reused for stats PARTIALS
  u16* rn    = (u16*)(ws + 16777216);   // 8 MB; reused for final stats
  u16* cond  = (u16*)(ws + 25165824);   // 8 MB  [b,h,i,d]
  u16* refv  = (u16*)(ws + 33554432);   // 8 MB  [b,h,j,d]
  u16* condT = (u16*)(ws + 41943040);   // 8 MB  [b,h,d,j]
  u16* refvT = (u16*)(ws + 50331648);   // 8 MB  [b,h,d,j]
  u16* sim   = (u16*)(ws + 58720256);   // 64 MB [b,h,i,j]; then step-8 partials
  u16* cmT   = (u16*)(ws + 125829120);  // 64 MB [b,g,j,i]
  u16* WkT   = (u16*)(ws + 192937984);  // 6 MB  [1024,3072] bf16
  u16* WvT   = (u16*)(ws + 199229440);  // 4 MB  [1024,2048] bf16
  u16* WoT   = (u16*)(ws + 203423744);  // 2 MB  [1024,1024] bf16
  // stats partials (in cn region, free after step 2): 4 x 2 MB fp32
  float* RP = (float*)(ws + 8388608);
  float* RS = (float*)(ws + 8388608 + 2097152);
  float* CP = (float*)(ws + 8388608 + 4194304);
  float* CS = (float*)(ws + 8388608 + 6291456);
  // final stats (in rn region, free after step 2): 4 x 128 KB fp32
  float* rmax = (float*)(ws + 16777216);
  float* rrcp = (float*)(ws + 16777216 + 131072);
  float* cmax = (float*)(ws + 16777216 + 262144);
  float* crcp = (float*)(ws + 16777216 + 393216);
  u16* out_pre = (u16*)(ws + 0);

  // 1) LayerNorms (fp32 -> bf16), all three in one launch
  ln3_kernel<<<dim3(4096,3), 256, 0, stream>>>(x, ref, cinfo, ln_w, ln_b,
                                               cln_w, cln_b, xn, rn, cn);

  // 1b) weight convert+transpose fp32[K,N] -> bf16[N,K]
  wcvt_kernel<<<dim3(96,32,3), 256, 0, stream>>>(Wk, Wv, Wo, WkT, WvT, WoT);

  // 2) fused projections (4-phase pipelined BK=64):
  //    z=0 -> [xn|cn|rn]@Wk -> cond; z=1 -> [xn|rn]@Wv -> refv
  gemm_kernel<<<dim3(8,32,2), 256, 0, stream>>>(
      xn, cn, rn, xn, rn, WkT, WvT, cond, refv, nullptr,
      3072, 2048, DIM, 3072, 2048, 0, 0, 0, 0, 3, 3, 1, 1.0f);

  // 3) transposed copies for the PV/context GEMM B-operands (one launch)
  transpose2_kernel<<<dim3(4,32,64), 256, 0, stream>>>(cond, refv, condT, refvT);

  // 4+5) sim = cond @ refv^T * scale WITH fused softmax partial stats,
  //      then tiny partial-fold kernel -> rmax/rrcp/cmax/crcp
  gemmqk_kernel<<<dim3(8,8,32), 256, 0, stream>>>(cond, refv, sim, RP, RS, CP, CS);
  redstats_kernel<<<256, 256, 0, stream>>>(RP, RS, CP, CS, rmax, rrcp, cmax, crcp);

  // 6) both softmaxes + talking heads (am in-place over sim; cmT transposed)
  mix_kernel<<<dim3(32,32,4), 256, 0, stream>>>(sim, rmax, rrcp, cmax, crcp, thw, cthw, cmT);

  // 7) fused (4-phase pipelined): z<32: am@refvT -> out_pre (bf16 head-merge);
  //    z>=32: cmT@condT -> ctx out (fp32)
  gemm_kernel<<<dim3(1,8,64), 256, 0, stream>>>(
      sim, sim, sim, cmT, cmT, refvT, condT, out_pre, out + (size_t)BATCH*NSEQ*DIM, nullptr,
      1024, 1024, NSEQ, NSEQ, NSEQ, 0,
      (long)NSEQ*NSEQ, (long)DHEAD*NSEQ, 0, 1, 4, 32, 1.0f);

  // 8) final projection, split-K=4 + chunked XCD swizzle: partials into sim
  //    region (dead after step 7), then deterministic reduce + bias.
  gemm8_kernel<<<1024, 256, 0, stream>>>(out_pre, WoT, (float*)sim);
  red8_kernel<<<4096, 256, 0, stream>>>((const float*)sim, bo, out);
}

// Round 11
// 439.935 us; speedup vs baseline: 1.3504x; 1.0157x over previous
//
#include <hip/hip_runtime.h>
#include <hip/hip_bf16.h>
#include <stdint.h>

typedef unsigned short u16;
typedef __attribute__((ext_vector_type(8))) short bf16x8;
typedef __attribute__((ext_vector_type(4))) float f32x4;

#define HEADS 8
#define DHEAD 128
#define NSEQ 1024
#define BATCH 4
#define DIM 1024
#define ATT_SCALE 0.088388347648318447f  // 1/sqrt(128)

static __device__ __forceinline__ float bf2f(u16 u){
  union { unsigned int i; float f; } c; c.i = ((unsigned int)u) << 16; return c.f;
}
static __device__ __forceinline__ u16 f2bf(float f){
  union { float f; unsigned int i; } c; c.f = f;
  unsigned int x = c.i;
  return (u16)((x + 0x7fffu + ((x >> 16) & 1u)) >> 16);
}

// async global->LDS, 16B per lane, dest = wave-uniform base + lane*16
static __device__ __forceinline__ void gload_lds16(const void* g, void* l){
  __builtin_amdgcn_global_load_lds((__attribute__((address_space(1))) void*)(g),
                                   (__attribute__((address_space(3))) void*)(l),
                                   16, 0, 0);
}

// ---------------- LayerNorm x3 fused: fp32 in, bf16 out ---------------------
// grid (4096, 3): y=0 x->xn (ln), y=1 ref->rn (ln), y=2 cinfo->cn (cln)
__global__ __launch_bounds__(256)
void ln3_kernel(const float* __restrict__ x, const float* __restrict__ ref,
                const float* __restrict__ cinfo,
                const float* __restrict__ ln_w, const float* __restrict__ ln_b,
                const float* __restrict__ cln_w, const float* __restrict__ cln_b,
                u16* __restrict__ xn, u16* __restrict__ rn, u16* __restrict__ cn)
{
  const int z = blockIdx.y;
  const float* src = (z==0) ? x : (z==1) ? ref : cinfo;
  const float* w   = (z==2) ? cln_w : ln_w;
  const float* b   = (z==2) ? cln_b : ln_b;
  u16* out         = (z==0) ? xn : (z==1) ? rn : cn;

  const int row = blockIdx.x;
  const int t = threadIdx.x;
  const float* xr = src + (size_t)row * DIM;
  float4 v4 = *(const float4*)(xr + t*4);
  float v[4] = {v4.x, v4.y, v4.z, v4.w};
  float s = v[0]+v[1]+v[2]+v[3];
  __shared__ float red[256];
  red[t] = s; __syncthreads();
  for (int o=128;o;o>>=1){ if (t<o) red[t]+=red[t+o]; __syncthreads(); }
  const float mean = red[0] * (1.0f/DIM);
  __syncthreads();
  s = 0.f;
#pragma unroll
  for (int i=0;i<4;i++){ float d = v[i]-mean; s += d*d; }
  red[t] = s; __syncthreads();
  for (int o=128;o;o>>=1){ if (t<o) red[t]+=red[t+o]; __syncthreads(); }
  const float rstd = rsqrtf(red[0]*(1.0f/DIM) + 1e-5f);
  float4 w4 = *(const float4*)(w + t*4);
  float4 b4 = *(const float4*)(b + t*4);
  float wv[4] = {w4.x, w4.y, w4.z, w4.w};
  float bv[4] = {b4.x, b4.y, b4.z, b4.w};
  union { uint2 u; u16 s[4]; } ov;
#pragma unroll
  for (int i=0;i<4;i++)
    ov.s[i] = f2bf((v[i]-mean)*rstd*wv[i] + bv[i]);
  *(uint2*)(out + (size_t)row*DIM + t*4) = ov.u;
}

// -------- weight convert+transpose: fp32 [K,1024] -> bf16 [1024,K] ----------
__global__ __launch_bounds__(256)
void wcvt_kernel(const float* __restrict__ Wk, const float* __restrict__ Wv,
                 const float* __restrict__ Wo,
                 u16* __restrict__ WkT, u16* __restrict__ WvT, u16* __restrict__ WoT)
{
  const int z = blockIdx.z;
  const int K = (z==0) ? 3072 : (z==1) ? 2048 : 1024;
  if ((int)blockIdx.x*32 >= K) return;
  const float* W = (z==0) ? Wk : (z==1) ? Wv : Wo;
  u16* WT = (z==0) ? WkT : (z==1) ? WvT : WoT;
  __shared__ float tile[32][33];
  const int k0 = blockIdx.x*32, n0 = blockIdx.y*32;
  const int t = threadIdx.x, tc = t&31, tr = t>>5;
#pragma unroll
  for (int p=0;p<4;p++)
    tile[tr+p*8][tc] = W[(size_t)(k0+tr+p*8)*DIM + n0+tc];
  __syncthreads();
#pragma unroll
  for (int p=0;p<4;p++)
    WT[(size_t)(n0+tr+p*8)*K + k0+tc] = f2bf(tile[tc][tr+p*8]);
}

// ---------------- MFMA GEMM: dbuf + global_load_lds, conflict-free LDS ------
// C[M,N] = sum_k A[m,k]*B[k,n]. A bf16 K-major, <=3 segments of 1024 cols.
// B is bf16 BT [N,K] row-major (K-major operand). Dual-problem via z_split.
// Template BK = K-tile depth (32 or 64). BK=64 halves barriers per unit K.
// LDS layout per 32-k sub-tile: 8 blocks of 16 rows; slot l (16B) of block g
// holds [row=g*16+(l&15)][k-oct=l>>4] -> ds_read_b128 conflict-free.
// epi: 0 bf16 C[z*cp+m*ldc+n]*alpha | 1 bf16 head-merge | 2 fp32 +bias[n]
//      3 bf16 head-split (+ transposed head-split copy if CpT non-null)
//      4 fp32 head-merge
template<int BK>
__global__ __launch_bounds__(256)
void gemm_kernel(const u16* __restrict__ A0, const u16* __restrict__ A1,
                 const u16* __restrict__ A2, const u16* __restrict__ A0b,
                 const u16* __restrict__ A1b,
                 const u16* __restrict__ B1, const u16* __restrict__ B2,
                 void* __restrict__ Cv, void* __restrict__ Cv2,
                 void* __restrict__ CvT, void* __restrict__ Cv2T,
                 const float* __restrict__ bias,
                 int K1, int K2, int lda, int ldb1, int ldb2, int ldc,
                 long a_plane, long b_plane, long c_plane,
                 int epi1, int epi2, int z_split, float alpha)
{
  constexpr int SUBS = BK/32;
  __shared__ __attribute__((aligned(16))) u16 sA[2][SUBS*4096];
  __shared__ __attribute__((aligned(16))) u16 sB[2][SUBS*4096];
  const int t = threadIdx.x;
  const int m0 = blockIdx.y*128, n0 = blockIdx.x*128;
  const int zz = blockIdx.z;
  const bool side = (zz >= z_split);
  const int z = side ? (zz - z_split) : zz;
  const u16* a0 = (side ? A0b : A0) + (size_t)z*a_plane;
  const u16* a1 = (side ? A1b : A1) + (size_t)z*a_plane;
  const u16* a2 = A2 + (size_t)z*a_plane;
  const u16* bB = (side ? B2 : B1) + (size_t)z*b_plane;
  void* Cp  = side ? Cv2 : Cv;
  void* CpT = side ? Cv2T : CvT;
  const int EPI = side ? epi2 : epi1;
  const int K   = side ? K2 : K1;
  const int ldb = side ? ldb2 : ldb1;

  const int wave = t>>6, lane = t&63;
  const int wm = (wave>>1)*64, wn = (wave&1)*64;
  const int lm = lane&15, q = lane>>4;

  const f32x4 zero4 = {0.f,0.f,0.f,0.f};
  f32x4 acc[4][4];
#pragma unroll
  for (int i=0;i<4;i++)
#pragma unroll
    for (int j=0;j<4;j++) acc[i][j] = zero4;

  const int arowblk = wave*32;

  const int KT = K / BK;

  auto issueA = [&](int kt, int buf){
    const int kg = kt*BK, seg = kg>>10, ka = kg&1023;
    const u16* Ap = (seg==0) ? a0 : (seg==1 ? a1 : a2);
#pragma unroll
    for (int sub=0; sub<SUBS; ++sub)
#pragma unroll
      for (int rr=0; rr<2; ++rr){
        const int rb = arowblk + rr*16;
        gload_lds16(Ap + (size_t)(m0+rb+lm)*lda + (ka + sub*32 + q*8),
                    &sA[buf][sub*4096 + rb*32]);
      }
  };
  auto issueB = [&](int kt, int buf){
    const int kg = kt*BK;
#pragma unroll
    for (int sub=0; sub<SUBS; ++sub)
#pragma unroll
      for (int rr=0; rr<2; ++rr){
        const int rb = arowblk + rr*16;
        gload_lds16(bB + (size_t)(n0+rb+lm)*ldb + (kg + sub*32 + q*8),
                    &sB[buf][sub*4096 + rb*32]);
      }
  };

  issueA(0, 0);
  issueB(0, 0);

  int cur = 0;
  for (int kt=0; kt<KT; ++kt){
    __syncthreads();
    if (kt+1 < KT){
      issueA(kt+1, cur^1);
      issueB(kt+1, cur^1);
    }
#pragma unroll
    for (int sub=0; sub<SUBS; ++sub){
      bf16x8 af[4], bfr[4];
#pragma unroll
      for (int f=0; f<4; ++f){
        af[f]  = *(const bf16x8*)&sA[cur][sub*4096 + ((wm>>4)+f)*512 + lane*8];
        bfr[f] = *(const bf16x8*)&sB[cur][sub*4096 + ((wn>>4)+f)*512 + lane*8];
      }
#pragma unroll
      for (int fm=0; fm<4; ++fm)
#pragma unroll
        for (int fn=0; fn<4; ++fn)
          acc[fm][fn] = __builtin_amdgcn_mfma_f32_16x16x32_bf16(af[fm], bfr[fn], acc[fm][fn], 0, 0, 0);
    }
    cur ^= 1;
  }

#pragma unroll
  for (int fm=0; fm<4; ++fm){
#pragma unroll
    for (int fn=0; fn<4; ++fn){
#pragma unroll
      for (int r=0; r<4; ++r){
        const int m = m0 + wm + fm*16 + q*4 + r;
        const int n = n0 + wn + fn*16 + lm;
        float val = acc[fm][fn][r] * alpha;
        if (EPI == 0){
          ((u16*)Cp)[(size_t)z*c_plane + (size_t)m*ldc + n] = f2bf(val);
        } else if (EPI == 1){
          ((u16*)Cp)[((size_t)(z>>3)*NSEQ + m)*DIM + (size_t)(z&7)*DHEAD + n] = f2bf(val);
        } else if (EPI == 2){
          ((float*)Cp)[(size_t)m*ldc + n] = val + bias[n];
        } else if (EPI == 3){
          ((u16*)Cp)[(size_t)(((m>>10)*HEADS + (n>>7))*NSEQ + (m&1023))*DHEAD + (n&127)] = f2bf(val);
        } else {
          ((float*)Cp)[((size_t)(z>>3)*NSEQ + m)*DIM + (size_t)(z&7)*DHEAD + n] = val;
        }
      }
    }
  }

  // epi3 extension: transposed head-split copy [b*8+h][d][i] (for step-7 B-ops)
  if (EPI == 3 && CpT){
#pragma unroll
    for (int fm=0; fm<4; ++fm){
#pragma unroll
      for (int fn=0; fn<4; ++fn){
        const int mb = m0 + wm + fm*16 + q*4;       // r = 0..3 consecutive rows
        const int n  = n0 + wn + fn*16 + lm;
        union { uint2 u; u16 s[4]; } tv;
#pragma unroll
        for (int r=0; r<4; ++r) tv.s[r] = f2bf(acc[fm][fn][r] * alpha);
        *(uint2*)&((u16*)CpT)[((size_t)((mb>>10)*HEADS + (n>>7))*DHEAD + (n&127))*NSEQ + (mb&1023)] = tv.u;
      }
    }
  }
}

// -------- sim GEMM + fused softmax partial stats (steps 4+5) ---------------
__global__ __launch_bounds__(256)
void gemmqk_kernel(const u16* __restrict__ cond, const u16* __restrict__ refv,
                   u16* __restrict__ sim,
                   float* __restrict__ RP, float* __restrict__ RS,
                   float* __restrict__ CP, float* __restrict__ CS)
{
  __shared__ __attribute__((aligned(16))) u16 sA[2][4096];
  __shared__ __attribute__((aligned(16))) u16 sB[2][4096];
  const int t = threadIdx.x;
  const int m0 = blockIdx.y*128, n0 = blockIdx.x*128;
  const int z = blockIdx.z;
  const u16* A = cond + (size_t)z*NSEQ*DHEAD;
  const u16* B = refv + (size_t)z*NSEQ*DHEAD;

  const int wave = t>>6, lane = t&63;
  const int wm = (wave>>1)*64, wn = (wave&1)*64;
  const int lm = lane&15, q = lane>>4;

  const f32x4 zero4 = {0.f,0.f,0.f,0.f};
  f32x4 acc[4][4];
#pragma unroll
  for (int i=0;i<4;i++)
#pragma unroll
    for (int j=0;j<4;j++) acc[i][j] = zero4;

  const int arowblk = wave*32;

  auto issueA = [&](int kt, int buf){
    const int kg = kt<<5;
#pragma unroll
    for (int rr=0; rr<2; ++rr){
      const int rb = arowblk + rr*16;
      gload_lds16(A + (size_t)(m0+rb+lm)*DHEAD + (kg + q*8), &sA[buf][rb*32]);
    }
  };
  auto issueB = [&](int kt, int buf){
    const int kg = kt<<5;
#pragma unroll
    for (int rr=0; rr<2; ++rr){
      const int rb = arowblk + rr*16;
      gload_lds16(B + (size_t)(n0+rb+lm)*DHEAD + (kg + q*8), &sB[buf][rb*32]);
    }
  };

  issueA(0, 0); issueB(0, 0);

  int cur = 0;
  for (int kt=0; kt<4; ++kt){                 // K=128, BK=32
    __syncthreads();
    if (kt+1 < 4){
      issueA(kt+1, cur^1);
      issueB(kt+1, cur^1);
    }
    bf16x8 af[4], bfr[4];
#pragma unroll
    for (int f=0; f<4; ++f){
      af[f]  = *(const bf16x8*)&sA[cur][((wm>>4)+f)*512 + lane*8];
      bfr[f] = *(const bf16x8*)&sB[cur][((wn>>4)+f)*512 + lane*8];
    }
#pragma unroll
    for (int fm=0; fm<4; ++fm)
#pragma unroll
      for (int fn=0; fn<4; ++fn)
        acc[fm][fn] = __builtin_amdgcn_mfma_f32_16x16x32_bf16(af[fm], bfr[fn], acc[fm][fn], 0, 0, 0);
    cur ^= 1;
  }

  // epilogue: store bf16 sim; keep bf16-rounded fp32 values in acc
#pragma unroll
  for (int fm=0; fm<4; ++fm){
#pragma unroll
    for (int fn=0; fn<4; ++fn){
#pragma unroll
      for (int r=0; r<4; ++r){
        const int m = m0 + wm + fm*16 + q*4 + r;
        const int n = n0 + wn + fn*16 + lm;
        const u16 bv = f2bf(acc[fm][fn][r] * ATT_SCALE);
        sim[((size_t)z*NSEQ + m)*NSEQ + n] = bv;
        acc[fm][fn][r] = bf2f(bv);
      }
    }
  }

  // row partials
  const int xg = blockIdx.x*2 + (wn>>6);
#pragma unroll
  for (int fm=0; fm<4; ++fm){
#pragma unroll
    for (int r=0; r<4; ++r){
      float rm = fmaxf(fmaxf(acc[fm][0][r], acc[fm][1][r]),
                       fmaxf(acc[fm][2][r], acc[fm][3][r]));
#pragma unroll
      for (int msk=1; msk<16; msk<<=1) rm = fmaxf(rm, __shfl_xor(rm, msk));
      float rs = __expf(acc[fm][0][r]-rm) + __expf(acc[fm][1][r]-rm)
               + __expf(acc[fm][2][r]-rm) + __expf(acc[fm][3][r]-rm);
#pragma unroll
      for (int msk=1; msk<16; msk<<=1) rs += __shfl_xor(rs, msk);
      if (lm == 0){
        const int m = m0 + wm + fm*16 + q*4 + r;
        RP[((size_t)z*NSEQ + m)*16 + xg] = rm;
        RS[((size_t)z*NSEQ + m)*16 + xg] = rs;
      }
    }
  }

  // col partials
  const int yg = blockIdx.y*2 + (wm>>6);
#pragma unroll
  for (int fn=0; fn<4; ++fn){
    float cm = -1e30f;
#pragma unroll
    for (int fm=0; fm<4; ++fm)
#pragma unroll
      for (int r=0; r<4; ++r) cm = fmaxf(cm, acc[fm][fn][r]);
    cm = fmaxf(cm, __shfl_xor(cm, 16));
    cm = fmaxf(cm, __shfl_xor(cm, 32));
    float cs = 0.f;
#pragma unroll
    for (int fm=0; fm<4; ++fm)
#pragma unroll
      for (int r=0; r<4; ++r) cs += __expf(acc[fm][fn][r]-cm);
    cs += __shfl_xor(cs, 16);
    cs += __shfl_xor(cs, 32);
    if (q == 0){
      const int n = n0 + wn + fn*16 + lm;
      CP[((size_t)z*NSEQ + n)*16 + yg] = cm;
      CS[((size_t)z*NSEQ + n)*16 + yg] = cs;
    }
  }
}

// -------- fold 16 partials per row/col -> rmax/rrcp, cmax/crcp --------------
__global__ __launch_bounds__(256)
void redstats_kernel(const float* __restrict__ RP, const float* __restrict__ RS,
                     const float* __restrict__ CP, const float* __restrict__ CS,
                     float* __restrict__ rmax, float* __restrict__ rrcp,
                     float* __restrict__ cmax, float* __restrict__ crcp)
{
  const int gid = blockIdx.x*256 + threadIdx.x;
  const bool isrow = gid < 32768;
  const int item = isrow ? gid : gid - 32768;
  const float* P = isrow ? RP : CP;
  const float* S = isrow ? RS : CS;
  float M = -1e30f;
#pragma unroll
  for (int g=0; g<16; g++) M = fmaxf(M, P[(size_t)item*16 + g]);
  float s = 0.f;
#pragma unroll
  for (int g=0; g<16; g++) s += S[(size_t)item*16 + g] * __expf(P[(size_t)item*16 + g] - M);
  if (isrow){ rmax[item] = M; rrcp[item] = 1.0f/s; }
  else      { cmax[item] = M; crcp[item] = 1.0f/s; }
}

// ------- split-K final projection: out_pre[4096,1024] @ WoT -> partials -----
__global__ __launch_bounds__(256)
void gemm8_kernel(const u16* __restrict__ A, const u16* __restrict__ B,
                  float* __restrict__ P)
{
  __shared__ __attribute__((aligned(16))) u16 sA[2][4096];
  __shared__ __attribute__((aligned(16))) u16 sB[2][4096];
  const int t = threadIdx.x;
  const int bid = blockIdx.x;
  const int w = (bid & 7)*128 + (bid >> 3);
  const int x = w & 7;          // N tile (0..7)
  const int y = (w >> 3) & 31;  // M tile (0..31)
  const int s = w >> 8;         // K slice (0..3)
  const int m0 = y*128, n0 = x*128, k0 = s*256;

  const int wave = t>>6, lane = t&63;
  const int wm = (wave>>1)*64, wn = (wave&1)*64;
  const int lm = lane&15, q = lane>>4;

  const f32x4 zero4 = {0.f,0.f,0.f,0.f};
  f32x4 acc[4][4];
#pragma unroll
  for (int i=0;i<4;i++)
#pragma unroll
    for (int j=0;j<4;j++) acc[i][j] = zero4;

  const int arowblk = wave*32;

  auto issueA = [&](int kt, int buf){
    const int kg = k0 + (kt<<5);
#pragma unroll
    for (int rr=0; rr<2; ++rr){
      const int rb = arowblk + rr*16;
      gload_lds16(A + (size_t)(m0+rb+lm)*1024 + (kg + q*8), &sA[buf][rb*32]);
    }
  };
  auto issueB = [&](int kt, int buf){
    const int kg = k0 + (kt<<5);
#pragma unroll
    for (int rr=0; rr<2; ++rr){
      const int rb = arowblk + rr*16;
      gload_lds16(B + (size_t)(n0+rb+lm)*1024 + (kg + q*8), &sB[buf][rb*32]);
    }
  };

  issueA(0, 0); issueB(0, 0);

  int cur = 0;
  for (int kt=0; kt<8; ++kt){
    __syncthreads();
    if (kt+1 < 8){
      issueA(kt+1, cur^1);
      issueB(kt+1, cur^1);
    }
    bf16x8 af[4], bfr[4];
#pragma unroll
    for (int f=0; f<4; ++f){
      af[f]  = *(const bf16x8*)&sA[cur][((wm>>4)+f)*512 + lane*8];
      bfr[f] = *(const bf16x8*)&sB[cur][((wn>>4)+f)*512 + lane*8];
    }
#pragma unroll
    for (int fm=0; fm<4; ++fm)
#pragma unroll
      for (int fn=0; fn<4; ++fn)
        acc[fm][fn] = __builtin_amdgcn_mfma_f32_16x16x32_bf16(af[fm], bfr[fn], acc[fm][fn], 0, 0, 0);
    cur ^= 1;
  }

  float* Pp = P + (size_t)s*4194304;   // 4096*1024 per slice
#pragma unroll
  for (int fm=0; fm<4; ++fm){
#pragma unroll
    for (int fn=0; fn<4; ++fn){
#pragma unroll
      for (int r=0; r<4; ++r){
        const int m = m0 + wm + fm*16 + q*4 + r;
        const int n = n0 + wn + fn*16 + lm;
        Pp[(size_t)m*1024 + n] = acc[fm][fn][r];
      }
    }
  }
}

// ------- reduce 4 fp32 partial planes + bias -> out (fp32) ------------------
__global__ __launch_bounds__(256)
void red8_kernel(const float* __restrict__ P, const float* __restrict__ bias,
                 float* __restrict__ out)
{
  const int idx = blockIdx.x*256 + threadIdx.x;   // float4 index, 1M total
  const float4* P4 = (const float4*)P;
  float4 a = P4[idx];
  float4 b = P4[idx + 1048576];
  float4 c = P4[idx + 2097152];
  float4 d = P4[idx + 3145728];
  float4 bb = ((const float4*)bias)[idx & 255];
  float4 o;
  o.x = a.x + b.x + c.x + d.x + bb.x;
  o.y = a.y + b.y + c.y + d.y + bb.y;
  o.z = a.z + b.z + c.z + d.z + bb.z;
  o.w = a.w + b.w + c.w + d.w + bb.w;
  ((float4*)out)[idx] = o;
}

// ---------------- softmax + talking-heads mix ----------------
__global__ __launch_bounds__(256)
void mix_kernel(u16* simam,
                const float* __restrict__ rmax, const float* __restrict__ rrcp,
                const float* __restrict__ cmax, const float* __restrict__ crcp,
                const float* __restrict__ thw, const float* __restrict__ cthw,
                u16* __restrict__ cmT)
{
  __shared__ float s_th[64], s_cth[64];
  __shared__ u16 s_cm[8][32][33];
  const int t = threadIdx.x;
  if (t < 64){ s_th[t] = thw[t]; s_cth[t] = cthw[t]; }
  __syncthreads();
  const int b = blockIdx.z, i0 = blockIdx.y*32, j0 = blockIdx.x*32;
  const int tj = t & 31, ti = t >> 5;
  for (int p=0;p<4;p++){
    const int i = ti + p*8;
    float a[8], c[8];
#pragma unroll
    for (int h=0;h<8;h++){
      const int bh = b*8 + h;
      const float v = bf2f(simam[((size_t)bh*NSEQ + (i0+i))*NSEQ + j0 + tj]);
      a[h] = __expf(v - rmax[(size_t)bh*NSEQ + i0+i]) * rrcp[(size_t)bh*NSEQ + i0+i];
      c[h] = __expf(v - cmax[(size_t)bh*NSEQ + j0+tj]) * crcp[(size_t)bh*NSEQ + j0+tj];
    }
#pragma unroll
    for (int g=0;g<8;g++){
      float sa = 0.f, sc = 0.f;
#pragma unroll
      for (int h=0;h<8;h++){ sa += s_th[g*8+h]*a[h]; sc += s_cth[g*8+h]*c[h]; }
      simam[((size_t)(b*8+g)*NSEQ + (i0+i))*NSEQ + j0 + tj] = f2bf(sa);
      s_cm[g][i][tj] = f2bf(sc);
    }
  }
  __syncthreads();
#pragma unroll
  for (int g=0;g<8;g++){
#pragma unroll
    for (int p=0;p<4;p++){
      const int j = ti + p*8;
      cmT[((size_t)(b*8+g)*NSEQ + (j0+j))*NSEQ + i0 + tj] = s_cm[g][tj][j];
    }
  }
}

extern "C" void kernel_launch(void* const* d_in, const int* in_sizes, int n_in,
                              void* d_out, int out_size, void* d_ws, size_t ws_size,
                              hipStream_t stream)
{
  const float* x     = (const float*)d_in[0];
  const float* cinfo = (const float*)d_in[1];
  const float* ref   = (const float*)d_in[2];
  const float* ln_w  = (const float*)d_in[3];
  const float* ln_b  = (const float*)d_in[4];
  const float* cln_w = (const float*)d_in[5];
  const float* cln_b = (const float*)d_in[6];
  const float* Wk    = (const float*)d_in[7];
  const float* Wv    = (const float*)d_in[8];
  const float* Wo    = (const float*)d_in[9];
  const float* bo    = (const float*)d_in[10];
  const float* thw   = (const float*)d_in[11];
  const float* cthw  = (const float*)d_in[12];
  float* out = (float*)d_out;

  char* ws = (char*)d_ws;
  u16* xn    = (u16*)(ws + 0);          // 8 MB; reused as out_pre
  u16* cn    = (u16*)(ws + 8388608);    // 8 MB; reused for stats PARTIALS
  u16* rn    = (u16*)(ws + 16777216);   // 8 MB; reused for final stats
  u16* cond  = (u16*)(ws + 25165824);   // 8 MB  [b,h,i,d]
  u16* refv  = (u16*)(ws + 33554432);   // 8 MB  [b,h,j,d]
  u16* condT = (u16*)(ws + 41943040);   // 8 MB  [b,h,d,j]
  u16* refvT = (u16*)(ws + 50331648);   // 8 MB  [b,h,d,j]
  u16* sim   = (u16*)(ws + 58720256);   // 64 MB [b,h,i,j]; then step-8 partials
  u16* cmT   = (u16*)(ws + 125829120);  // 64 MB [b,g,j,i]
  u16* WkT   = (u16*)(ws + 192937984);  // 6 MB  [1024,3072] bf16
  u16* WvT   = (u16*)(ws + 199229440);  // 4 MB  [1024,2048] bf16
  u16* WoT   = (u16*)(ws + 203423744);  // 2 MB  [1024,1024] bf16
  // stats partials (in cn region, free after step 2): 4 x 2 MB fp32
  float* RP = (float*)(ws + 8388608);
  float* RS = (float*)(ws + 8388608 + 2097152);
  float* CP = (float*)(ws + 8388608 + 4194304);
  float* CS = (float*)(ws + 8388608 + 6291456);
  // final stats (in rn region, free after step 2): 4 x 128 KB fp32
  float* rmax = (float*)(ws + 16777216);
  float* rrcp = (float*)(ws + 16777216 + 131072);
  float* cmax = (float*)(ws + 16777216 + 262144);
  float* crcp = (float*)(ws + 16777216 + 393216);
  u16* out_pre = (u16*)(ws + 0);

  // 1) LayerNorms (fp32 -> bf16), all three in one launch
  ln3_kernel<<<dim3(4096,3), 256, 0, stream>>>(x, ref, cinfo, ln_w, ln_b,
                                               cln_w, cln_b, xn, rn, cn);

  // 1b) weight convert+transpose fp32[K,N] -> bf16[N,K]
  wcvt_kernel<<<dim3(96,32,3), 256, 0, stream>>>(Wk, Wv, Wo, WkT, WvT, WoT);

  // 2) fused projections (2-barrier BK=64, r9-verified) + fused transposed
  //    copies in the epilogue (replaces transpose2_kernel):
  //    z=0 -> [xn|cn|rn]@Wk -> cond + condT; z=1 -> [xn|rn]@Wv -> refv + refvT
  gemm_kernel<64><<<dim3(8,32,2), 256, 0, stream>>>(
      xn, cn, rn, xn, rn, WkT, WvT, cond, refv, condT, refvT, nullptr,
      3072, 2048, DIM, 3072, 2048, 0, 0, 0, 0, 3, 3, 1, 1.0f);

  // 4+5) sim = cond @ refv^T * scale WITH fused softmax partial stats,
  //      then tiny partial-fold kernel -> rmax/rrcp/cmax/crcp
  gemmqk_kernel<<<dim3(8,8,32), 256, 0, stream>>>(cond, refv, sim, RP, RS, CP, CS);
  redstats_kernel<<<256, 256, 0, stream>>>(RP, RS, CP, CS, rmax, rrcp, cmax, crcp);

  // 6) both softmaxes + talking heads (am in-place over sim; cmT transposed)
  mix_kernel<<<dim3(32,32,4), 256, 0, stream>>>(sim, rmax, rrcp, cmax, crcp, thw, cthw, cmT);

  // 7) fused (2-barrier BK=64): z<32: am@refvT -> out_pre (bf16 head-merge);
  //    z>=32: cmT@condT -> ctx out (fp32)
  gemm_kernel<64><<<dim3(1,8,64), 256, 0, stream>>>(
      sim, sim, sim, cmT, cmT, refvT, condT, out_pre, out + (size_t)BATCH*NSEQ*DIM,
      nullptr, nullptr, nullptr,
      1024, 1024, NSEQ, NSEQ, NSEQ, 0,
      (long)NSEQ*NSEQ, (long)DHEAD*NSEQ, 0, 1, 4, 32, 1.0f);

  // 8) final projection, split-K=4 + chunked XCD swizzle: partials into sim
  //    region (dead after step 7), then deterministic reduce + bias.
  gemm8_kernel<<<1024, 256, 0, stream>>>(out_pre, WoT, (float*)sim);
  red8_kernel<<<4096, 256, 0, stream>>>((const float*)sim, bo, out);
}